// Round 1
// baseline (551.114 us; speedup 1.0000x reference)
//
#include <hip/hip_runtime.h>
#include <hip/hip_bf16.h>
#include <cstdint>
#include <cstddef>

#define IN_DIM 1024
#define OUT_DIM 1024
#define NE 8
#define NTOK 8192

typedef __bf16 bf16x8 __attribute__((ext_vector_type(8)));
typedef float f32x4 __attribute__((ext_vector_type(4)));

// RNE float -> bf16 bits
__device__ __forceinline__ unsigned short f2bf(float f) {
    unsigned u = __float_as_uint(f);
    unsigned r = 0x7fffu + ((u >> 16) & 1u);
    return (unsigned short)((u + r) >> 16);
}

// async global->LDS, 16B per lane. lds must be wave-uniform base; g is per-lane.
__device__ __forceinline__ void async16(void* lds, const void* g) {
    __builtin_amdgcn_global_load_lds(
        (const __attribute__((address_space(1))) unsigned int*)g,
        (__attribute__((address_space(3))) unsigned int*)lds,
        16, 0, 0);
}

// ---------------- weight convert + transpose: [K][N] fp32 -> [N][K] bf16 ----
__global__ __launch_bounds__(256) void convert_transpose_kernel(
    const float* __restrict__ w1, const float* __restrict__ w2,
    unsigned short* __restrict__ w1T, unsigned short* __restrict__ w2T) {
    __shared__ float tile[64][68];
    int z = blockIdx.z; // 0..7 -> w1 experts, 8..15 -> w2 experts
    const float* src = (z < 8) ? (w1 + (size_t)z * IN_DIM * OUT_DIM)
                               : (w2 + (size_t)(z - 8) * OUT_DIM * OUT_DIM);
    unsigned short* dst = (z < 8) ? (w1T + (size_t)z * IN_DIM * OUT_DIM)
                                  : (w2T + (size_t)(z - 8) * OUT_DIM * OUT_DIM);
    int kt = blockIdx.x * 64, nt = blockIdx.y * 64;
    int t = threadIdx.x;
    int r = t >> 2, cq = (t & 3) * 16;
#pragma unroll
    for (int q = 0; q < 4; ++q) {
        float4 v = *(const float4*)(src + (size_t)(kt + r) * 1024 + nt + cq + q * 4);
        tile[r][cq + q * 4 + 0] = v.x;
        tile[r][cq + q * 4 + 1] = v.y;
        tile[r][cq + q * 4 + 2] = v.z;
        tile[r][cq + q * 4 + 3] = v.w;
    }
    __syncthreads();
    int n = t >> 2, kq = (t & 3) * 16;
#pragma unroll
    for (int q = 0; q < 4; ++q) {
        ushort4 o;
        o.x = f2bf(tile[kq + q * 4 + 0][n]);
        o.y = f2bf(tile[kq + q * 4 + 1][n]);
        o.z = f2bf(tile[kq + q * 4 + 2][n]);
        o.w = f2bf(tile[kq + q * 4 + 3][n]);
        *(ushort4*)(dst + (size_t)(nt + n) * 1024 + kt + kq + q * 4) = o;
    }
}

// ---------------- router: logits, top-2, softmax, bucket, x->bf16, out init --
__global__ __launch_bounds__(256) void router_kernel(
    const float* __restrict__ x, const float* __restrict__ rw,
    const float* __restrict__ rb, const float* __restrict__ b2,
    unsigned short* __restrict__ xb, float* __restrict__ out,
    float* __restrict__ gating, int* __restrict__ bidx,
    float* __restrict__ bw, int* __restrict__ cnt) {
    __shared__ float srw[NE * IN_DIM]; // transposed: srw[e*1024 + k], conflict-free reads
    int t = threadIdx.x;
#pragma unroll
    for (int i = 0; i < 4; ++i) {
        int k = t + i * 256;
        float4 a = *(const float4*)(rw + (size_t)k * NE);
        float4 b = *(const float4*)(rw + (size_t)k * NE + 4);
        srw[0 * IN_DIM + k] = a.x; srw[1 * IN_DIM + k] = a.y;
        srw[2 * IN_DIM + k] = a.z; srw[3 * IN_DIM + k] = a.w;
        srw[4 * IN_DIM + k] = b.x; srw[5 * IN_DIM + k] = b.y;
        srw[6 * IN_DIM + k] = b.z; srw[7 * IN_DIM + k] = b.w;
    }
    __syncthreads();
    int wave = t >> 6, lane = t & 63;
    int tok = blockIdx.x * 4 + wave;
    const float* xrow = x + (size_t)tok * IN_DIM;
    unsigned short* xbrow = xb + (size_t)tok * IN_DIM;
    float acc[NE] = {0, 0, 0, 0, 0, 0, 0, 0};
#pragma unroll
    for (int i = 0; i < 16; ++i) {
        int k = lane + i * 64;
        float xv = xrow[k];
        xbrow[k] = f2bf(xv);
#pragma unroll
        for (int e = 0; e < NE; ++e) acc[e] += xv * srw[e * IN_DIM + k];
    }
#pragma unroll
    for (int e = 0; e < NE; ++e) {
#pragma unroll
        for (int off = 32; off > 0; off >>= 1) acc[e] += __shfl_xor(acc[e], off);
        acc[e] += rb[e];
    }
    // top-2 (lowest index wins ties, matching lax.top_k)
    int e0 = 0; float v0 = acc[0];
#pragma unroll
    for (int e = 1; e < NE; ++e) if (acc[e] > v0) { v0 = acc[e]; e0 = e; }
    int e1 = -1; float v1 = -3.4e38f;
#pragma unroll
    for (int e = 0; e < NE; ++e) if (e != e0 && acc[e] > v1) { v1 = acc[e]; e1 = e; }
    float tg = expf(v1 - v0);
    float inv = 1.0f / (1.0f + tg);
    float g0 = inv, g1 = tg * inv;
    if (lane < NE) gating[(size_t)tok * NE + lane] = (lane == e0) ? g0 : ((lane == e1) ? g1 : 0.0f);
    if (lane == 0) {
        int p0 = atomicAdd(&cnt[e0], 1);
        bidx[e0 * NTOK + p0] = tok; bw[e0 * NTOK + p0] = g0;
        int p1 = atomicAdd(&cnt[e1], 1);
        bidx[e1 * NTOK + p1] = tok; bw[e1 * NTOK + p1] = g1;
    }
    const float* b2r0 = b2 + (size_t)e0 * OUT_DIM;
    const float* b2r1 = b2 + (size_t)e1 * OUT_DIM;
    float* orow = out + (size_t)tok * OUT_DIM;
#pragma unroll
    for (int i = 0; i < 16; ++i) {
        int c = lane + i * 64;
        orow[c] = g0 * b2r0[c] + g1 * b2r1[c];
    }
}

// ---------------- 8-entry exclusive scan ------------------------------------
__global__ void scan_kernel(const int* __restrict__ cnt, int* __restrict__ base) {
    if (threadIdx.x == 0) {
        int s = 0;
        for (int e = 0; e < NE; ++e) { base[e] = s; s += cnt[e]; }
    }
}

// ---------------- GEMM1: H = relu(gather(Xb) @ W1 + b1), bf16 out ----------
__global__ __launch_bounds__(256) void gemm1_kernel(
    const unsigned short* __restrict__ xb, const unsigned short* __restrict__ w1T,
    const float* __restrict__ b1, const int* __restrict__ bidx,
    const int* __restrict__ cnt, const int* __restrict__ base,
    unsigned short* __restrict__ H) {
    int e = blockIdx.z;
    int n_e = cnt[e];
    int mt = blockIdx.x;
    if (mt * 128 >= n_e) return;
    int nt = blockIdx.y;
    __shared__ __attribute__((aligned(16))) unsigned short As[128 * 64];
    __shared__ __attribute__((aligned(16))) unsigned short Bs[128 * 64];
    int t = threadIdx.x, wave = t >> 6, lane = t & 63;
    const int* be = bidx + e * NTOK;
    const unsigned short* agp[4]; const unsigned short* bgp[4];
    unsigned short* alds[4]; unsigned short* blds[4];
#pragma unroll
    for (int is = 0; is < 4; ++is) {
        int c = is * 256 + t;
        int row = c >> 3;
        int colg = ((c & 7) ^ (row & 7)) * 8; // XOR swizzle (elements)
        int gr = mt * 128 + row;
        int grc = gr < n_e ? gr : n_e - 1;
        agp[is] = xb + (size_t)be[grc] * IN_DIM + colg;
        bgp[is] = w1T + ((size_t)e * OUT_DIM + nt * 128 + row) * IN_DIM + colg;
        alds[is] = As + (is * 256 + wave * 64) * 8;
        blds[is] = Bs + (is * 256 + wave * 64) * 8;
    }
    int wm = wave & 1, wn = wave >> 1;
    int quad = lane >> 4, l15 = lane & 15, sw = l15 & 7;
    f32x4 zero4 = {0.f, 0.f, 0.f, 0.f};
    f32x4 acc[4][4];
#pragma unroll
    for (int i = 0; i < 4; ++i)
#pragma unroll
        for (int j = 0; j < 4; ++j) acc[i][j] = zero4;

    for (int kt = 0; kt < IN_DIM; kt += 64) {
#pragma unroll
        for (int is = 0; is < 4; ++is) {
            async16(alds[is], agp[is] + kt);
            async16(blds[is], bgp[is] + kt);
        }
        __syncthreads();
#pragma unroll
        for (int s = 0; s < 2; ++s) {
            int cidx = s * 4 + quad;
            bf16x8 av[4], bv[4];
#pragma unroll
            for (int i = 0; i < 4; ++i) {
                int m = wm * 64 + i * 16 + l15;
                av[i] = *(const bf16x8*)(As + m * 64 + ((cidx ^ sw) * 8));
            }
#pragma unroll
            for (int j = 0; j < 4; ++j) {
                int n = wn * 64 + j * 16 + l15;
                bv[j] = *(const bf16x8*)(Bs + n * 64 + ((cidx ^ sw) * 8));
            }
#pragma unroll
            for (int i = 0; i < 4; ++i)
#pragma unroll
                for (int j = 0; j < 4; ++j)
                    acc[i][j] = __builtin_amdgcn_mfma_f32_16x16x32_bf16(av[i], bv[j], acc[i][j], 0, 0, 0);
        }
        __syncthreads();
    }
    // epilogue: + b1, relu, bf16 store to packed H
    int hbase = base[e];
    const float* b1e = b1 + (size_t)e * OUT_DIM;
    int n0 = nt * 128 + wn * 64 + l15;
#pragma unroll
    for (int j = 0; j < 4; ++j) {
        int n = n0 + j * 16;
        float bias = b1e[n];
#pragma unroll
        for (int i = 0; i < 4; ++i) {
            int m0 = mt * 128 + wm * 64 + i * 16 + quad * 4;
#pragma unroll
            for (int r = 0; r < 4; ++r) {
                int gm = m0 + r;
                if (gm < n_e) {
                    float h = acc[i][j][r] + bias;
                    h = h > 0.f ? h : 0.f;
                    H[(size_t)(hbase + gm) * OUT_DIM + n] = f2bf(h);
                }
            }
        }
    }
}

// ---------------- GEMM2: out[tok] += g * (H @ W2), fp32 atomics -------------
__global__ __launch_bounds__(256) void gemm2_kernel(
    const unsigned short* __restrict__ H, const unsigned short* __restrict__ w2T,
    const int* __restrict__ bidx, const float* __restrict__ bw,
    const int* __restrict__ cnt, const int* __restrict__ base,
    float* __restrict__ out) {
    int e = blockIdx.z;
    int n_e = cnt[e];
    int mt = blockIdx.x;
    if (mt * 128 >= n_e) return;
    int nt = blockIdx.y;
    __shared__ __attribute__((aligned(16))) unsigned short As[128 * 64];
    __shared__ __attribute__((aligned(16))) unsigned short Bs[128 * 64];
    int t = threadIdx.x, wave = t >> 6, lane = t & 63;
    int hbase = base[e];
    const unsigned short* agp[4]; const unsigned short* bgp[4];
    unsigned short* alds[4]; unsigned short* blds[4];
#pragma unroll
    for (int is = 0; is < 4; ++is) {
        int c = is * 256 + t;
        int row = c >> 3;
        int colg = ((c & 7) ^ (row & 7)) * 8;
        int gr = mt * 128 + row;
        int grc = gr < n_e ? gr : n_e - 1;
        agp[is] = H + (size_t)(hbase + grc) * OUT_DIM + colg;
        bgp[is] = w2T + ((size_t)e * OUT_DIM + nt * 128 + row) * OUT_DIM + colg;
        alds[is] = As + (is * 256 + wave * 64) * 8;
        blds[is] = Bs + (is * 256 + wave * 64) * 8;
    }
    int wm = wave & 1, wn = wave >> 1;
    int quad = lane >> 4, l15 = lane & 15, sw = l15 & 7;
    f32x4 zero4 = {0.f, 0.f, 0.f, 0.f};
    f32x4 acc[4][4];
#pragma unroll
    for (int i = 0; i < 4; ++i)
#pragma unroll
        for (int j = 0; j < 4; ++j) acc[i][j] = zero4;

    for (int kt = 0; kt < OUT_DIM; kt += 64) {
#pragma unroll
        for (int is = 0; is < 4; ++is) {
            async16(alds[is], agp[is] + kt);
            async16(blds[is], bgp[is] + kt);
        }
        __syncthreads();
#pragma unroll
        for (int s = 0; s < 2; ++s) {
            int cidx = s * 4 + quad;
            bf16x8 av[4], bv[4];
#pragma unroll
            for (int i = 0; i < 4; ++i) {
                int m = wm * 64 + i * 16 + l15;
                av[i] = *(const bf16x8*)(As + m * 64 + ((cidx ^ sw) * 8));
            }
#pragma unroll
            for (int j = 0; j < 4; ++j) {
                int n = wn * 64 + j * 16 + l15;
                bv[j] = *(const bf16x8*)(Bs + n * 64 + ((cidx ^ sw) * 8));
            }
#pragma unroll
            for (int i = 0; i < 4; ++i)
#pragma unroll
                for (int j = 0; j < 4; ++j)
                    acc[i][j] = __builtin_amdgcn_mfma_f32_16x16x32_bf16(av[i], bv[j], acc[i][j], 0, 0, 0);
        }
        __syncthreads();
    }
    // epilogue: scatter-accumulate weighted outputs
    int n0 = nt * 128 + wn * 64 + l15;
#pragma unroll
    for (int i = 0; i < 4; ++i) {
        int m0 = mt * 128 + wm * 64 + i * 16 + quad * 4;
#pragma unroll
        for (int r = 0; r < 4; ++r) {
            int gm = m0 + r;
            if (gm < n_e) {
                int tok = bidx[e * NTOK + gm];
                float wgt = bw[e * NTOK + gm];
                float* orow = out + (size_t)tok * OUT_DIM;
#pragma unroll
                for (int j = 0; j < 4; ++j)
                    atomicAdd(&orow[n0 + j * 16], wgt * acc[i][j][r]);
            }
        }
    }
}

extern "C" void kernel_launch(void* const* d_in, const int* in_sizes, int n_in,
                              void* d_out, int out_size, void* d_ws, size_t ws_size,
                              hipStream_t stream) {
    const float* x  = (const float*)d_in[0];
    const float* rw = (const float*)d_in[1];
    const float* rb = (const float*)d_in[2];
    const float* w1 = (const float*)d_in[3];
    const float* b1 = (const float*)d_in[4];
    const float* w2 = (const float*)d_in[5];
    const float* b2 = (const float*)d_in[6];
    float* out = (float*)d_out;                       // fused [8192,1024]
    float* gating = out + (size_t)NTOK * OUT_DIM;     // gating [8192,8]

    char* ws = (char*)d_ws;
    // ws layout (bytes): requires ~80.5 MB
    unsigned short* xb  = (unsigned short*)(ws + 0);          // 16 MiB
    unsigned short* w1T = (unsigned short*)(ws + 16777216);   // 16 MiB
    unsigned short* w2T = (unsigned short*)(ws + 33554432);   // 16 MiB
    unsigned short* H   = (unsigned short*)(ws + 50331648);   // 32 MiB
    int*   bidx = (int*)(ws + 83886080);                      // 256 KiB
    float* bw   = (float*)(ws + 84148224);                    // 256 KiB
    int*   cnt  = (int*)(ws + 84410368);                      // 32 B
    int*   base = (int*)(ws + 84410400);                      // 32 B

    hipMemsetAsync(cnt, 0, 64, stream);
    convert_transpose_kernel<<<dim3(16, 16, 16), 256, 0, stream>>>(w1, w2, w1T, w2T);
    router_kernel<<<NTOK / 4, 256, 0, stream>>>(x, rw, rb, b2, xb, out, gating, bidx, bw, cnt);
    scan_kernel<<<1, 64, 0, stream>>>(cnt, base);
    gemm1_kernel<<<dim3(64, 8, 8), 256, 0, stream>>>(xb, w1T, b1, bidx, cnt, base, H);
    gemm2_kernel<<<dim3(64, 8, 8), 256, 0, stream>>>(H, w2T, bidx, bw, cnt, base, out);
    (void)in_sizes; (void)n_in; (void)out_size; (void)ws_size;
}

// Round 2
// 407.644 us; speedup vs baseline: 1.3519x; 1.3519x over previous
//
#include <hip/hip_runtime.h>
#include <hip/hip_bf16.h>
#include <cstdint>
#include <cstddef>

#define IN_DIM 1024
#define OUT_DIM 1024
#define NE 8
#define NTOK 8192

typedef __bf16 bf16x8 __attribute__((ext_vector_type(8)));
typedef float f32x4 __attribute__((ext_vector_type(4)));

// RNE float -> bf16 bits
__device__ __forceinline__ unsigned short f2bf(float f) {
    unsigned u = __float_as_uint(f);
    unsigned r = 0x7fffu + ((u >> 16) & 1u);
    return (unsigned short)((u + r) >> 16);
}

// async global->LDS, 16B per lane. lds must be wave-uniform base; g is per-lane.
__device__ __forceinline__ void async16(void* lds, const void* g) {
    __builtin_amdgcn_global_load_lds(
        (const __attribute__((address_space(1))) unsigned int*)g,
        (__attribute__((address_space(3))) unsigned int*)lds,
        16, 0, 0);
}

// ---------------- weight convert + transpose: [K][N] fp32 -> [N][K] bf16 ----
__global__ __launch_bounds__(256) void convert_transpose_kernel(
    const float* __restrict__ w1, const float* __restrict__ w2,
    unsigned short* __restrict__ w1T, unsigned short* __restrict__ w2T) {
    __shared__ float tile[64][68];
    int z = blockIdx.z; // 0..7 -> w1 experts, 8..15 -> w2 experts
    const float* src = (z < 8) ? (w1 + (size_t)z * IN_DIM * OUT_DIM)
                               : (w2 + (size_t)(z - 8) * OUT_DIM * OUT_DIM);
    unsigned short* dst = (z < 8) ? (w1T + (size_t)z * IN_DIM * OUT_DIM)
                                  : (w2T + (size_t)(z - 8) * OUT_DIM * OUT_DIM);
    int kt = blockIdx.x * 64, nt = blockIdx.y * 64;
    int t = threadIdx.x;
    int r = t >> 2, cq = (t & 3) * 16;
#pragma unroll
    for (int q = 0; q < 4; ++q) {
        float4 v = *(const float4*)(src + (size_t)(kt + r) * 1024 + nt + cq + q * 4);
        tile[r][cq + q * 4 + 0] = v.x;
        tile[r][cq + q * 4 + 1] = v.y;
        tile[r][cq + q * 4 + 2] = v.z;
        tile[r][cq + q * 4 + 3] = v.w;
    }
    __syncthreads();
    int n = t >> 2, kq = (t & 3) * 16;
#pragma unroll
    for (int q = 0; q < 4; ++q) {
        ushort4 o;
        o.x = f2bf(tile[kq + q * 4 + 0][n]);
        o.y = f2bf(tile[kq + q * 4 + 1][n]);
        o.z = f2bf(tile[kq + q * 4 + 2][n]);
        o.w = f2bf(tile[kq + q * 4 + 3][n]);
        *(ushort4*)(dst + (size_t)(nt + n) * 1024 + kt + kq + q * 4) = o;
    }
}

// ---------------- router: logits, top-2, softmax, x->bf16, out init ---------
// NO atomics: emits per-token records (enc, gw); bucketing happens in
// bucket_kernel. R1 post-mortem: 16K contended fetch-adds on 8 addresses
// serialized ~200us.
__global__ __launch_bounds__(256) void router_kernel(
    const float* __restrict__ x, const float* __restrict__ rw,
    const float* __restrict__ rb, const float* __restrict__ b2,
    unsigned short* __restrict__ xb, float* __restrict__ out,
    float* __restrict__ gating, int* __restrict__ enc,
    float2* __restrict__ gw) {
    __shared__ float srw[NE * IN_DIM]; // transposed: srw[e*1024 + k]
    int t = threadIdx.x;
#pragma unroll
    for (int i = 0; i < 4; ++i) {
        int k = t + i * 256;
        float4 a = *(const float4*)(rw + (size_t)k * NE);
        float4 b = *(const float4*)(rw + (size_t)k * NE + 4);
        srw[0 * IN_DIM + k] = a.x; srw[1 * IN_DIM + k] = a.y;
        srw[2 * IN_DIM + k] = a.z; srw[3 * IN_DIM + k] = a.w;
        srw[4 * IN_DIM + k] = b.x; srw[5 * IN_DIM + k] = b.y;
        srw[6 * IN_DIM + k] = b.z; srw[7 * IN_DIM + k] = b.w;
    }
    __syncthreads();
    int wave = t >> 6, lane = t & 63;
    int tok = blockIdx.x * 4 + wave;
    const float* xrow = x + (size_t)tok * IN_DIM;
    unsigned short* xbrow = xb + (size_t)tok * IN_DIM;
    float acc[NE] = {0, 0, 0, 0, 0, 0, 0, 0};
#pragma unroll
    for (int i = 0; i < 4; ++i) {
        int k = i * 256 + lane * 4;
        float4 xv = *(const float4*)(xrow + k);
        ushort4 o;
        o.x = f2bf(xv.x); o.y = f2bf(xv.y); o.z = f2bf(xv.z); o.w = f2bf(xv.w);
        *(ushort4*)(xbrow + k) = o;
#pragma unroll
        for (int e = 0; e < NE; ++e) {
            float4 wv = *(const float4*)(srw + e * IN_DIM + k);
            acc[e] = fmaf(xv.x, wv.x, fmaf(xv.y, wv.y, fmaf(xv.z, wv.z, fmaf(xv.w, wv.w, acc[e]))));
        }
    }
#pragma unroll
    for (int e = 0; e < NE; ++e) {
#pragma unroll
        for (int off = 32; off > 0; off >>= 1) acc[e] += __shfl_xor(acc[e], off);
        acc[e] += rb[e];
    }
    // top-2 (lowest index wins ties, matching lax.top_k)
    int e0 = 0; float v0 = acc[0];
#pragma unroll
    for (int e = 1; e < NE; ++e) if (acc[e] > v0) { v0 = acc[e]; e0 = e; }
    int e1 = -1; float v1 = -3.4e38f;
#pragma unroll
    for (int e = 0; e < NE; ++e) if (e != e0 && acc[e] > v1) { v1 = acc[e]; e1 = e; }
    float tg = __expf(v1 - v0);
    float inv = 1.0f / (1.0f + tg);
    float g0 = inv, g1 = tg * inv;
    if (lane < NE) gating[(size_t)tok * NE + lane] = (lane == e0) ? g0 : ((lane == e1) ? g1 : 0.0f);
    if (lane == 0) {
        enc[tok] = e0 | (e1 << 8);
        gw[tok] = make_float2(g0, g1);
    }
    const float* b2r0 = b2 + (size_t)e0 * OUT_DIM;
    const float* b2r1 = b2 + (size_t)e1 * OUT_DIM;
    float* orow = out + (size_t)tok * OUT_DIM;
#pragma unroll
    for (int i = 0; i < 4; ++i) {
        int c = i * 256 + lane * 4;
        float4 a = *(const float4*)(b2r0 + c);
        float4 b = *(const float4*)(b2r1 + c);
        float4 o;
        o.x = fmaf(g0, a.x, g1 * b.x);
        o.y = fmaf(g0, a.y, g1 * b.y);
        o.z = fmaf(g0, a.z, g1 * b.z);
        o.w = fmaf(g0, a.w, g1 * b.w);
        *(float4*)(orow + c) = o;
    }
}

// ---------------- bucket: deterministic per-expert compaction, no atomics ---
__global__ __launch_bounds__(256) void bucket_kernel(
    const int* __restrict__ enc, const float2* __restrict__ gw,
    int* __restrict__ bidx, float* __restrict__ bw, int* __restrict__ cnt) {
    int e = blockIdx.x;
    __shared__ int wsum[4];
    __shared__ int runbase;
    int t = threadIdx.x, wave = t >> 6, lane = t & 63;
    if (t == 0) runbase = 0;
    __syncthreads();
    for (int c0 = 0; c0 < NTOK; c0 += 256) {
        int tok = c0 + t;
        int v = enc[tok];
        int e0 = v & 0xff, e1 = (v >> 8) & 0xff;
        bool sel = (e0 == e) || (e1 == e);
        float g = 0.f;
        if (sel) { float2 gg = gw[tok]; g = (e0 == e) ? gg.x : gg.y; }
        unsigned long long m = __ballot(sel);
        int pos = __popcll(m & ((1ull << lane) - 1ull));
        if (lane == 0) wsum[wave] = __popcll(m);
        __syncthreads();
        int wb = runbase;
        for (int w = 0; w < wave; ++w) wb += wsum[w];
        if (sel) { bidx[e * NTOK + wb + pos] = tok; bw[e * NTOK + wb + pos] = g; }
        __syncthreads();
        if (t == 0) runbase += wsum[0] + wsum[1] + wsum[2] + wsum[3];
        __syncthreads();
    }
    if (t == 0) cnt[e] = runbase;
}

// ---------------- 8-entry exclusive scan ------------------------------------
__global__ void scan_kernel(const int* __restrict__ cnt, int* __restrict__ base) {
    if (threadIdx.x == 0) {
        int s = 0;
        for (int e = 0; e < NE; ++e) { base[e] = s; s += cnt[e]; }
    }
}

// ---------------- GEMM1: H = relu(gather(Xb) @ W1 + b1), bf16 out ----------
__global__ __launch_bounds__(256) void gemm1_kernel(
    const unsigned short* __restrict__ xb, const unsigned short* __restrict__ w1T,
    const float* __restrict__ b1, const int* __restrict__ bidx,
    const int* __restrict__ cnt, const int* __restrict__ base,
    unsigned short* __restrict__ H) {
    int e = blockIdx.z;
    int n_e = cnt[e];
    int mt = blockIdx.x;
    if (mt * 128 >= n_e) return;
    int nt = blockIdx.y;
    __shared__ __attribute__((aligned(16))) unsigned short As[128 * 64];
    __shared__ __attribute__((aligned(16))) unsigned short Bs[128 * 64];
    int t = threadIdx.x, wave = t >> 6, lane = t & 63;
    const int* be = bidx + e * NTOK;
    const unsigned short* agp[4]; const unsigned short* bgp[4];
    unsigned short* alds[4]; unsigned short* blds[4];
#pragma unroll
    for (int is = 0; is < 4; ++is) {
        int c = is * 256 + t;
        int row = c >> 3;
        int colg = ((c & 7) ^ (row & 7)) * 8; // XOR swizzle (elements)
        int gr = mt * 128 + row;
        int grc = gr < n_e ? gr : n_e - 1;
        agp[is] = xb + (size_t)be[grc] * IN_DIM + colg;
        bgp[is] = w1T + ((size_t)e * OUT_DIM + nt * 128 + row) * IN_DIM + colg;
        alds[is] = As + (is * 256 + wave * 64) * 8;
        blds[is] = Bs + (is * 256 + wave * 64) * 8;
    }
    int wm = wave & 1, wn = wave >> 1;
    int quad = lane >> 4, l15 = lane & 15, sw = l15 & 7;
    f32x4 zero4 = {0.f, 0.f, 0.f, 0.f};
    f32x4 acc[4][4];
#pragma unroll
    for (int i = 0; i < 4; ++i)
#pragma unroll
        for (int j = 0; j < 4; ++j) acc[i][j] = zero4;

    for (int kt = 0; kt < IN_DIM; kt += 64) {
#pragma unroll
        for (int is = 0; is < 4; ++is) {
            async16(alds[is], agp[is] + kt);
            async16(blds[is], bgp[is] + kt);
        }
        __syncthreads();
#pragma unroll
        for (int s = 0; s < 2; ++s) {
            int cidx = s * 4 + quad;
            bf16x8 av[4], bv[4];
#pragma unroll
            for (int i = 0; i < 4; ++i) {
                int m = wm * 64 + i * 16 + l15;
                av[i] = *(const bf16x8*)(As + m * 64 + ((cidx ^ sw) * 8));
            }
#pragma unroll
            for (int j = 0; j < 4; ++j) {
                int n = wn * 64 + j * 16 + l15;
                bv[j] = *(const bf16x8*)(Bs + n * 64 + ((cidx ^ sw) * 8));
            }
#pragma unroll
            for (int i = 0; i < 4; ++i)
#pragma unroll
                for (int j = 0; j < 4; ++j)
                    acc[i][j] = __builtin_amdgcn_mfma_f32_16x16x32_bf16(av[i], bv[j], acc[i][j], 0, 0, 0);
        }
        __syncthreads();
    }
    // epilogue: + b1, relu, bf16 store to packed H
    int hbase = base[e];
    const float* b1e = b1 + (size_t)e * OUT_DIM;
    int n0 = nt * 128 + wn * 64 + l15;
#pragma unroll
    for (int j = 0; j < 4; ++j) {
        int n = n0 + j * 16;
        float bias = b1e[n];
#pragma unroll
        for (int i = 0; i < 4; ++i) {
            int m0 = mt * 128 + wm * 64 + i * 16 + quad * 4;
#pragma unroll
            for (int r = 0; r < 4; ++r) {
                int gm = m0 + r;
                if (gm < n_e) {
                    float h = acc[i][j][r] + bias;
                    h = h > 0.f ? h : 0.f;
                    H[(size_t)(hbase + gm) * OUT_DIM + n] = f2bf(h);
                }
            }
        }
    }
}

// ---------------- GEMM2: out[tok] += g * (H @ W2), fp32 atomics -------------
__global__ __launch_bounds__(256) void gemm2_kernel(
    const unsigned short* __restrict__ H, const unsigned short* __restrict__ w2T,
    const int* __restrict__ bidx, const float* __restrict__ bw,
    const int* __restrict__ cnt, const int* __restrict__ base,
    float* __restrict__ out) {
    int e = blockIdx.z;
    int n_e = cnt[e];
    int mt = blockIdx.x;
    if (mt * 128 >= n_e) return;
    int nt = blockIdx.y;
    __shared__ __attribute__((aligned(16))) unsigned short As[128 * 64];
    __shared__ __attribute__((aligned(16))) unsigned short Bs[128 * 64];
    int t = threadIdx.x, wave = t >> 6, lane = t & 63;
    int hbase = base[e];
    const unsigned short* agp[4]; const unsigned short* bgp[4];
    unsigned short* alds[4]; unsigned short* blds[4];
#pragma unroll
    for (int is = 0; is < 4; ++is) {
        int c = is * 256 + t;
        int row = c >> 3;
        int colg = ((c & 7) ^ (row & 7)) * 8;
        int gr = mt * 128 + row;
        int grc = gr < n_e ? gr : n_e - 1;
        agp[is] = H + (size_t)(hbase + grc) * OUT_DIM + colg;
        bgp[is] = w2T + ((size_t)e * OUT_DIM + nt * 128 + row) * OUT_DIM + colg;
        alds[is] = As + (is * 256 + wave * 64) * 8;
        blds[is] = Bs + (is * 256 + wave * 64) * 8;
    }
    int wm = wave & 1, wn = wave >> 1;
    int quad = lane >> 4, l15 = lane & 15, sw = l15 & 7;
    f32x4 zero4 = {0.f, 0.f, 0.f, 0.f};
    f32x4 acc[4][4];
#pragma unroll
    for (int i = 0; i < 4; ++i)
#pragma unroll
        for (int j = 0; j < 4; ++j) acc[i][j] = zero4;

    for (int kt = 0; kt < OUT_DIM; kt += 64) {
#pragma unroll
        for (int is = 0; is < 4; ++is) {
            async16(alds[is], agp[is] + kt);
            async16(blds[is], bgp[is] + kt);
        }
        __syncthreads();
#pragma unroll
        for (int s = 0; s < 2; ++s) {
            int cidx = s * 4 + quad;
            bf16x8 av[4], bv[4];
#pragma unroll
            for (int i = 0; i < 4; ++i) {
                int m = wm * 64 + i * 16 + l15;
                av[i] = *(const bf16x8*)(As + m * 64 + ((cidx ^ sw) * 8));
            }
#pragma unroll
            for (int j = 0; j < 4; ++j) {
                int n = wn * 64 + j * 16 + l15;
                bv[j] = *(const bf16x8*)(Bs + n * 64 + ((cidx ^ sw) * 8));
            }
#pragma unroll
            for (int i = 0; i < 4; ++i)
#pragma unroll
                for (int j = 0; j < 4; ++j)
                    acc[i][j] = __builtin_amdgcn_mfma_f32_16x16x32_bf16(av[i], bv[j], acc[i][j], 0, 0, 0);
        }
        __syncthreads();
    }
    // epilogue: scatter-accumulate weighted outputs
    int n0 = nt * 128 + wn * 64 + l15;
#pragma unroll
    for (int i = 0; i < 4; ++i) {
        int m0 = mt * 128 + wm * 64 + i * 16 + quad * 4;
#pragma unroll
        for (int r = 0; r < 4; ++r) {
            int gm = m0 + r;
            if (gm < n_e) {
                int tok = bidx[e * NTOK + gm];
                float wgt = bw[e * NTOK + gm];
                float* orow = out + (size_t)tok * OUT_DIM;
#pragma unroll
                for (int j = 0; j < 4; ++j)
                    atomicAdd(&orow[n0 + j * 16], wgt * acc[i][j][r]);
            }
        }
    }
}

extern "C" void kernel_launch(void* const* d_in, const int* in_sizes, int n_in,
                              void* d_out, int out_size, void* d_ws, size_t ws_size,
                              hipStream_t stream) {
    const float* x  = (const float*)d_in[0];
    const float* rw = (const float*)d_in[1];
    const float* rb = (const float*)d_in[2];
    const float* w1 = (const float*)d_in[3];
    const float* b1 = (const float*)d_in[4];
    const float* w2 = (const float*)d_in[5];
    const float* b2 = (const float*)d_in[6];
    float* out = (float*)d_out;                       // fused [8192,1024]
    float* gating = out + (size_t)NTOK * OUT_DIM;     // gating [8192,8]

    char* ws = (char*)d_ws;
    unsigned short* xb  = (unsigned short*)(ws + 0);          // 16 MiB
    unsigned short* w1T = (unsigned short*)(ws + 16777216);   // 16 MiB
    unsigned short* w2T = (unsigned short*)(ws + 33554432);   // 16 MiB
    unsigned short* H   = (unsigned short*)(ws + 50331648);   // 32 MiB
    int*   bidx = (int*)(ws + 83886080);                      // 256 KiB
    float* bw   = (float*)(ws + 84148224);                    // 256 KiB
    int*   cnt  = (int*)(ws + 84410368);                      // 32 B
    int*   base = (int*)(ws + 84410400);                      // 32 B
    // enc/gw overlap the H region: consumed by bucket_kernel before gemm1
    // writes H (stream-ordered), so no extra ws needed.
    int*    enc = (int*)(ws + 50331648);                      // 32 KiB
    float2* gw  = (float2*)(ws + 50331648 + 32768);           // 64 KiB

    convert_transpose_kernel<<<dim3(16, 16, 16), 256, 0, stream>>>(w1, w2, w1T, w2T);
    router_kernel<<<NTOK / 4, 256, 0, stream>>>(x, rw, rb, b2, xb, out, gating, enc, gw);
    bucket_kernel<<<NE, 256, 0, stream>>>(enc, gw, bidx, bw, cnt);
    scan_kernel<<<1, 64, 0, stream>>>(cnt, base);
    gemm1_kernel<<<dim3(64, 8, 8), 256, 0, stream>>>(xb, w1T, b1, bidx, cnt, base, H);
    gemm2_kernel<<<dim3(64, 8, 8), 256, 0, stream>>>(H, w2T, bidx, bw, cnt, base, out);
    (void)in_sizes; (void)n_in; (void)out_size; (void)ws_size;
}

// Round 3
// 371.095 us; speedup vs baseline: 1.4851x; 1.0985x over previous
//
#include <hip/hip_runtime.h>
#include <hip/hip_bf16.h>
#include <cstdint>
#include <cstddef>

#define IN_DIM 1024
#define OUT_DIM 1024
#define NE 8
#define NTOK 8192

typedef __bf16 bf16x8 __attribute__((ext_vector_type(8)));
typedef float f32x4 __attribute__((ext_vector_type(4)));

// RNE float -> bf16 bits
__device__ __forceinline__ unsigned short f2bf(float f) {
    unsigned u = __float_as_uint(f);
    unsigned r = 0x7fffu + ((u >> 16) & 1u);
    return (unsigned short)((u + r) >> 16);
}

// decode packed bf16 pair (u32) -> two floats
__device__ __forceinline__ void bf2x(unsigned u, float& lo, float& hi) {
    lo = __uint_as_float(u << 16);
    hi = __uint_as_float(u & 0xffff0000u);
}

// async global->LDS, 16B per lane. lds must be wave-uniform base; g is per-lane.
__device__ __forceinline__ void async16(void* lds, const void* g) {
    __builtin_amdgcn_global_load_lds(
        (const __attribute__((address_space(1))) unsigned int*)g,
        (__attribute__((address_space(3))) unsigned int*)lds,
        16, 0, 0);
}

// ---------------- weight convert + transpose: [K][N] fp32 -> [N][K] bf16 ----
__global__ __launch_bounds__(256) void convert_transpose_kernel(
    const float* __restrict__ w1, const float* __restrict__ w2,
    unsigned short* __restrict__ w1T, unsigned short* __restrict__ w2T) {
    __shared__ float tile[64][68];
    int z = blockIdx.z; // 0..7 -> w1 experts, 8..15 -> w2 experts
    const float* src = (z < 8) ? (w1 + (size_t)z * IN_DIM * OUT_DIM)
                               : (w2 + (size_t)(z - 8) * OUT_DIM * OUT_DIM);
    unsigned short* dst = (z < 8) ? (w1T + (size_t)z * IN_DIM * OUT_DIM)
                                  : (w2T + (size_t)(z - 8) * OUT_DIM * OUT_DIM);
    int kt = blockIdx.x * 64, nt = blockIdx.y * 64;
    int t = threadIdx.x;
    int r = t >> 2, cq = (t & 3) * 16;
#pragma unroll
    for (int q = 0; q < 4; ++q) {
        float4 v = *(const float4*)(src + (size_t)(kt + r) * 1024 + nt + cq + q * 4);
        tile[r][cq + q * 4 + 0] = v.x;
        tile[r][cq + q * 4 + 1] = v.y;
        tile[r][cq + q * 4 + 2] = v.z;
        tile[r][cq + q * 4 + 3] = v.w;
    }
    __syncthreads();
    int n = t >> 2, kq = (t & 3) * 16;
#pragma unroll
    for (int q = 0; q < 4; ++q) {
        ushort4 o;
        o.x = f2bf(tile[kq + q * 4 + 0][n]);
        o.y = f2bf(tile[kq + q * 4 + 1][n]);
        o.z = f2bf(tile[kq + q * 4 + 2][n]);
        o.w = f2bf(tile[kq + q * 4 + 3][n]);
        *(ushort4*)(dst + (size_t)(nt + n) * 1024 + kt + kq + q * 4) = o;
    }
}

// ---------------- router: logits, top-2, softmax, x->bf16 -------------------
// No atomics, no out-init (combine handles b2). Emits (enc, gw) records.
__global__ __launch_bounds__(256) void router_kernel(
    const float* __restrict__ x, const float* __restrict__ rw,
    const float* __restrict__ rb,
    unsigned short* __restrict__ xb,
    float* __restrict__ gating, int* __restrict__ enc,
    float2* __restrict__ gw) {
    __shared__ float srw[NE * IN_DIM]; // transposed: srw[e*1024 + k]
    int t = threadIdx.x;
#pragma unroll
    for (int i = 0; i < 4; ++i) {
        int k = t + i * 256;
        float4 a = *(const float4*)(rw + (size_t)k * NE);
        float4 b = *(const float4*)(rw + (size_t)k * NE + 4);
        srw[0 * IN_DIM + k] = a.x; srw[1 * IN_DIM + k] = a.y;
        srw[2 * IN_DIM + k] = a.z; srw[3 * IN_DIM + k] = a.w;
        srw[4 * IN_DIM + k] = b.x; srw[5 * IN_DIM + k] = b.y;
        srw[6 * IN_DIM + k] = b.z; srw[7 * IN_DIM + k] = b.w;
    }
    __syncthreads();
    int wave = t >> 6, lane = t & 63;
    int tok = blockIdx.x * 4 + wave;
    const float* xrow = x + (size_t)tok * IN_DIM;
    unsigned short* xbrow = xb + (size_t)tok * IN_DIM;
    float acc[NE] = {0, 0, 0, 0, 0, 0, 0, 0};
#pragma unroll
    for (int i = 0; i < 4; ++i) {
        int k = i * 256 + lane * 4;
        float4 xv = *(const float4*)(xrow + k);
        ushort4 o;
        o.x = f2bf(xv.x); o.y = f2bf(xv.y); o.z = f2bf(xv.z); o.w = f2bf(xv.w);
        *(ushort4*)(xbrow + k) = o;
#pragma unroll
        for (int e = 0; e < NE; ++e) {
            float4 wv = *(const float4*)(srw + e * IN_DIM + k);
            acc[e] = fmaf(xv.x, wv.x, fmaf(xv.y, wv.y, fmaf(xv.z, wv.z, fmaf(xv.w, wv.w, acc[e]))));
        }
    }
#pragma unroll
    for (int e = 0; e < NE; ++e) {
#pragma unroll
        for (int off = 32; off > 0; off >>= 1) acc[e] += __shfl_xor(acc[e], off);
        acc[e] += rb[e];
    }
    // top-2 (lowest index wins ties, matching lax.top_k)
    int e0 = 0; float v0 = acc[0];
#pragma unroll
    for (int e = 1; e < NE; ++e) if (acc[e] > v0) { v0 = acc[e]; e0 = e; }
    int e1 = -1; float v1 = -3.4e38f;
#pragma unroll
    for (int e = 0; e < NE; ++e) if (e != e0 && acc[e] > v1) { v1 = acc[e]; e1 = e; }
    float tg = __expf(v1 - v0);
    float inv = 1.0f / (1.0f + tg);
    float g0 = inv, g1 = tg * inv;
    if (lane < NE) gating[(size_t)tok * NE + lane] = (lane == e0) ? g0 : ((lane == e1) ? g1 : 0.0f);
    if (lane == 0) {
        enc[tok] = e0 | (e1 << 8);
        gw[tok] = make_float2(g0, g1);
    }
}

// ---------------- bucket: deterministic per-expert compaction, no atomics ---
// Also emits the inverse map: slots[2*tok+which] = (e<<13) | local_idx.
__global__ __launch_bounds__(256) void bucket_kernel(
    const int* __restrict__ enc, const float2* __restrict__ gw,
    int* __restrict__ bidx, int* __restrict__ slots, int* __restrict__ cnt) {
    int e = blockIdx.x;
    __shared__ int wsum[4];
    __shared__ int runbase;
    int t = threadIdx.x, wave = t >> 6, lane = t & 63;
    if (t == 0) runbase = 0;
    __syncthreads();
    for (int c0 = 0; c0 < NTOK; c0 += 256) {
        int tok = c0 + t;
        int v = enc[tok];
        int e0 = v & 0xff, e1 = (v >> 8) & 0xff;
        bool sel = (e0 == e) || (e1 == e);
        unsigned long long m = __ballot(sel);
        int pos = __popcll(m & ((1ull << lane) - 1ull));
        if (lane == 0) wsum[wave] = __popcll(m);
        __syncthreads();
        int wb = runbase;
        for (int w = 0; w < wave; ++w) wb += wsum[w];
        if (sel) {
            int p = wb + pos;
            bidx[e * NTOK + p] = tok;
            int which = (e0 == e) ? 0 : 1;
            slots[2 * tok + which] = (e << 13) | p;
        }
        __syncthreads();
        if (t == 0) runbase += wsum[0] + wsum[1] + wsum[2] + wsum[3];
        __syncthreads();
    }
    if (t == 0) cnt[e] = runbase;
}

// ---------------- 8-entry exclusive scan ------------------------------------
__global__ void scan_kernel(const int* __restrict__ cnt, int* __restrict__ base) {
    if (threadIdx.x == 0) {
        int s = 0;
        for (int e = 0; e < NE; ++e) { base[e] = s; s += cnt[e]; }
    }
}

// ---------------- GEMM1: H = relu(gather(Xb) @ W1 + b1), bf16 out ----------
__global__ __launch_bounds__(256) void gemm1_kernel(
    const unsigned short* __restrict__ xb, const unsigned short* __restrict__ w1T,
    const float* __restrict__ b1, const int* __restrict__ bidx,
    const int* __restrict__ cnt, const int* __restrict__ base,
    unsigned short* __restrict__ H) {
    int e = blockIdx.z;
    int n_e = cnt[e];
    int mt = blockIdx.x;
    if (mt * 128 >= n_e) return;
    int nt = blockIdx.y;
    __shared__ __attribute__((aligned(16))) unsigned short As[128 * 64];
    __shared__ __attribute__((aligned(16))) unsigned short Bs[128 * 64];
    int t = threadIdx.x, wave = t >> 6, lane = t & 63;
    const int* be = bidx + e * NTOK;
    const unsigned short* agp[4]; const unsigned short* bgp[4];
    unsigned short* alds[4]; unsigned short* blds[4];
#pragma unroll
    for (int is = 0; is < 4; ++is) {
        int c = is * 256 + t;
        int row = c >> 3;
        int colg = ((c & 7) ^ (row & 7)) * 8; // XOR swizzle (elements)
        int gr = mt * 128 + row;
        int grc = gr < n_e ? gr : n_e - 1;
        agp[is] = xb + (size_t)be[grc] * IN_DIM + colg;
        bgp[is] = w1T + ((size_t)e * OUT_DIM + nt * 128 + row) * IN_DIM + colg;
        alds[is] = As + (is * 256 + wave * 64) * 8;
        blds[is] = Bs + (is * 256 + wave * 64) * 8;
    }
    int wm = wave & 1, wn = wave >> 1;
    int quad = lane >> 4, l15 = lane & 15, sw = l15 & 7;
    f32x4 zero4 = {0.f, 0.f, 0.f, 0.f};
    f32x4 acc[4][4];
#pragma unroll
    for (int i = 0; i < 4; ++i)
#pragma unroll
        for (int j = 0; j < 4; ++j) acc[i][j] = zero4;

    for (int kt = 0; kt < IN_DIM; kt += 64) {
#pragma unroll
        for (int is = 0; is < 4; ++is) {
            async16(alds[is], agp[is] + kt);
            async16(blds[is], bgp[is] + kt);
        }
        __syncthreads();
#pragma unroll
        for (int s = 0; s < 2; ++s) {
            int cidx = s * 4 + quad;
            bf16x8 av[4], bv[4];
#pragma unroll
            for (int i = 0; i < 4; ++i) {
                int m = wm * 64 + i * 16 + l15;
                av[i] = *(const bf16x8*)(As + m * 64 + ((cidx ^ sw) * 8));
            }
#pragma unroll
            for (int j = 0; j < 4; ++j) {
                int n = wn * 64 + j * 16 + l15;
                bv[j] = *(const bf16x8*)(Bs + n * 64 + ((cidx ^ sw) * 8));
            }
#pragma unroll
            for (int i = 0; i < 4; ++i)
#pragma unroll
                for (int j = 0; j < 4; ++j)
                    acc[i][j] = __builtin_amdgcn_mfma_f32_16x16x32_bf16(av[i], bv[j], acc[i][j], 0, 0, 0);
        }
        __syncthreads();
    }
    // epilogue: + b1, relu, bf16 store to packed H
    int hbase = base[e];
    const float* b1e = b1 + (size_t)e * OUT_DIM;
    int n0 = nt * 128 + wn * 64 + l15;
#pragma unroll
    for (int j = 0; j < 4; ++j) {
        int n = n0 + j * 16;
        float bias = b1e[n];
#pragma unroll
        for (int i = 0; i < 4; ++i) {
            int m0 = mt * 128 + wm * 64 + i * 16 + quad * 4;
#pragma unroll
            for (int r = 0; r < 4; ++r) {
                int gm = m0 + r;
                if (gm < n_e) {
                    float h = acc[i][j][r] + bias;
                    h = h > 0.f ? h : 0.f;
                    H[(size_t)(hbase + gm) * OUT_DIM + n] = f2bf(h);
                }
            }
        }
    }
}

// ---------------- GEMM2: Y = H @ W2 (packed bf16, plain stores) -------------
__global__ __launch_bounds__(256) void gemm2_kernel(
    const unsigned short* __restrict__ H, const unsigned short* __restrict__ w2T,
    const int* __restrict__ cnt, const int* __restrict__ base,
    unsigned short* __restrict__ Y) {
    int e = blockIdx.z;
    int n_e = cnt[e];
    int mt = blockIdx.x;
    if (mt * 128 >= n_e) return;
    int nt = blockIdx.y;
    __shared__ __attribute__((aligned(16))) unsigned short As[128 * 64];
    __shared__ __attribute__((aligned(16))) unsigned short Bs[128 * 64];
    int t = threadIdx.x, wave = t >> 6, lane = t & 63;
    int hbase = base[e];
    const unsigned short* agp[4]; const unsigned short* bgp[4];
    unsigned short* alds[4]; unsigned short* blds[4];
#pragma unroll
    for (int is = 0; is < 4; ++is) {
        int c = is * 256 + t;
        int row = c >> 3;
        int colg = ((c & 7) ^ (row & 7)) * 8;
        int gr = mt * 128 + row;
        int grc = gr < n_e ? gr : n_e - 1;
        agp[is] = H + (size_t)(hbase + grc) * OUT_DIM + colg;
        bgp[is] = w2T + ((size_t)e * OUT_DIM + nt * 128 + row) * OUT_DIM + colg;
        alds[is] = As + (is * 256 + wave * 64) * 8;
        blds[is] = Bs + (is * 256 + wave * 64) * 8;
    }
    int wm = wave & 1, wn = wave >> 1;
    int quad = lane >> 4, l15 = lane & 15, sw = l15 & 7;
    f32x4 zero4 = {0.f, 0.f, 0.f, 0.f};
    f32x4 acc[4][4];
#pragma unroll
    for (int i = 0; i < 4; ++i)
#pragma unroll
        for (int j = 0; j < 4; ++j) acc[i][j] = zero4;

    for (int kt = 0; kt < OUT_DIM; kt += 64) {
#pragma unroll
        for (int is = 0; is < 4; ++is) {
            async16(alds[is], agp[is] + kt);
            async16(blds[is], bgp[is] + kt);
        }
        __syncthreads();
#pragma unroll
        for (int s = 0; s < 2; ++s) {
            int cidx = s * 4 + quad;
            bf16x8 av[4], bv[4];
#pragma unroll
            for (int i = 0; i < 4; ++i) {
                int m = wm * 64 + i * 16 + l15;
                av[i] = *(const bf16x8*)(As + m * 64 + ((cidx ^ sw) * 8));
            }
#pragma unroll
            for (int j = 0; j < 4; ++j) {
                int n = wn * 64 + j * 16 + l15;
                bv[j] = *(const bf16x8*)(Bs + n * 64 + ((cidx ^ sw) * 8));
            }
#pragma unroll
            for (int i = 0; i < 4; ++i)
#pragma unroll
                for (int j = 0; j < 4; ++j)
                    acc[i][j] = __builtin_amdgcn_mfma_f32_16x16x32_bf16(av[i], bv[j], acc[i][j], 0, 0, 0);
        }
        __syncthreads();
    }
    // epilogue: plain bf16 stores to packed Y (no atomics; combine later)
    int n0 = nt * 128 + wn * 64 + l15;
#pragma unroll
    for (int i = 0; i < 4; ++i) {
        int m0 = mt * 128 + wm * 64 + i * 16 + quad * 4;
#pragma unroll
        for (int r = 0; r < 4; ++r) {
            int gm = m0 + r;
            if (gm < n_e) {
                unsigned short* yrow = Y + (size_t)(hbase + gm) * OUT_DIM;
#pragma unroll
                for (int j = 0; j < 4; ++j)
                    yrow[n0 + j * 16] = f2bf(acc[i][j][r]);
            }
        }
    }
}

// ---------------- combine: out[tok] = g0*(Y[r0]+b2[e0]) + g1*(Y[r1]+b2[e1]) -
__global__ __launch_bounds__(256) void combine_kernel(
    const unsigned short* __restrict__ Y, const float* __restrict__ b2,
    const float2* __restrict__ gw, const int* __restrict__ slots,
    const int* __restrict__ base, float* __restrict__ out) {
    int t = threadIdx.x, wave = t >> 6, lane = t & 63;
    int tok = blockIdx.x * 4 + wave;
    int s0 = slots[2 * tok], s1 = slots[2 * tok + 1];
    int e0 = s0 >> 13, e1 = s1 >> 13;
    int r0 = base[e0] + (s0 & 8191);
    int r1 = base[e1] + (s1 & 8191);
    float2 g = gw[tok];
    const unsigned short* y0 = Y + (size_t)r0 * OUT_DIM;
    const unsigned short* y1 = Y + (size_t)r1 * OUT_DIM;
    const float* c0 = b2 + (size_t)e0 * OUT_DIM;
    const float* c1 = b2 + (size_t)e1 * OUT_DIM;
    float* orow = out + (size_t)tok * OUT_DIM;
#pragma unroll
    for (int i = 0; i < 2; ++i) {
        int c = i * 512 + lane * 8;
        uint4 ua = *(const uint4*)(y0 + c);
        uint4 ub = *(const uint4*)(y1 + c);
        float a[8], b[8];
        bf2x(ua.x, a[0], a[1]); bf2x(ua.y, a[2], a[3]);
        bf2x(ua.z, a[4], a[5]); bf2x(ua.w, a[6], a[7]);
        bf2x(ub.x, b[0], b[1]); bf2x(ub.y, b[2], b[3]);
        bf2x(ub.z, b[4], b[5]); bf2x(ub.w, b[6], b[7]);
        float4 p0 = *(const float4*)(c0 + c);
        float4 p1 = *(const float4*)(c0 + c + 4);
        float4 q0 = *(const float4*)(c1 + c);
        float4 q1 = *(const float4*)(c1 + c + 4);
        float o[8];
        o[0] = g.x * (a[0] + p0.x) + g.y * (b[0] + q0.x);
        o[1] = g.x * (a[1] + p0.y) + g.y * (b[1] + q0.y);
        o[2] = g.x * (a[2] + p0.z) + g.y * (b[2] + q0.z);
        o[3] = g.x * (a[3] + p0.w) + g.y * (b[3] + q0.w);
        o[4] = g.x * (a[4] + p1.x) + g.y * (b[4] + q1.x);
        o[5] = g.x * (a[5] + p1.y) + g.y * (b[5] + q1.y);
        o[6] = g.x * (a[6] + p1.z) + g.y * (b[6] + q1.z);
        o[7] = g.x * (a[7] + p1.w) + g.y * (b[7] + q1.w);
        *(float4*)(orow + c) = make_float4(o[0], o[1], o[2], o[3]);
        *(float4*)(orow + c + 4) = make_float4(o[4], o[5], o[6], o[7]);
    }
}

extern "C" void kernel_launch(void* const* d_in, const int* in_sizes, int n_in,
                              void* d_out, int out_size, void* d_ws, size_t ws_size,
                              hipStream_t stream) {
    const float* x  = (const float*)d_in[0];
    const float* rw = (const float*)d_in[1];
    const float* rb = (const float*)d_in[2];
    const float* w1 = (const float*)d_in[3];
    const float* b1 = (const float*)d_in[4];
    const float* w2 = (const float*)d_in[5];
    const float* b2 = (const float*)d_in[6];
    float* out = (float*)d_out;                       // fused [8192,1024]
    float* gating = out + (size_t)NTOK * OUT_DIM;     // gating [8192,8]

    char* ws = (char*)d_ws;
    // ws layout (bytes). Y reuses [0,32MiB): xb+w1T are dead after gemm1
    // (stream-ordered). enc/gw consumed by bucket before gemm1 writes H.
    unsigned short* xb  = (unsigned short*)(ws + 0);          // 16 MiB
    unsigned short* Y   = (unsigned short*)(ws + 0);          // 32 MiB (gemm2+)
    unsigned short* w1T = (unsigned short*)(ws + 16777216);   // 16 MiB
    unsigned short* w2T = (unsigned short*)(ws + 33554432);   // 16 MiB
    unsigned short* H   = (unsigned short*)(ws + 50331648);   // 32 MiB
    int*   bidx  = (int*)(ws + 83886080);                     // 256 KiB
    int*   slots = (int*)(ws + 84148224);                     // 64 KiB
    int*   cnt   = (int*)(ws + 84213760);                     // 64 B
    int*   base  = (int*)(ws + 84213824);                     // 64 B
    int*    enc  = (int*)(ws + 84213888);                     // 32 KiB
    float2* gw   = (float2*)(ws + 84246656);                  // 64 KiB

    convert_transpose_kernel<<<dim3(16, 16, 16), 256, 0, stream>>>(w1, w2, w1T, w2T);
    router_kernel<<<NTOK / 4, 256, 0, stream>>>(x, rw, rb, xb, gating, enc, gw);
    bucket_kernel<<<NE, 256, 0, stream>>>(enc, gw, bidx, slots, cnt);
    scan_kernel<<<1, 64, 0, stream>>>(cnt, base);
    gemm1_kernel<<<dim3(64, 8, 8), 256, 0, stream>>>(xb, w1T, b1, bidx, cnt, base, H);
    gemm2_kernel<<<dim3(64, 8, 8), 256, 0, stream>>>(H, w2T, cnt, base, Y);
    combine_kernel<<<NTOK / 4, 256, 0, stream>>>(Y, b2, gw, slots, base, out);
    (void)in_sizes; (void)n_in; (void)out_size; (void)ws_size;
}

// Round 4
// 326.094 us; speedup vs baseline: 1.6900x; 1.1380x over previous
//
#include <hip/hip_runtime.h>
#include <hip/hip_bf16.h>
#include <cstdint>
#include <cstddef>

#define IN_DIM 1024
#define OUT_DIM 1024
#define NE 8
#define NTOK 8192

typedef __bf16 bf16x8 __attribute__((ext_vector_type(8)));
typedef float f32x4 __attribute__((ext_vector_type(4)));

// RNE float -> bf16 bits
__device__ __forceinline__ unsigned short f2bf(float f) {
    unsigned u = __float_as_uint(f);
    unsigned r = 0x7fffu + ((u >> 16) & 1u);
    return (unsigned short)((u + r) >> 16);
}

// decode packed bf16 pair (u32) -> two floats
__device__ __forceinline__ void bf2x(unsigned u, float& lo, float& hi) {
    lo = __uint_as_float(u << 16);
    hi = __uint_as_float(u & 0xffff0000u);
}

// async global->LDS, 16B per lane. lds must be wave-uniform base; g is per-lane.
__device__ __forceinline__ void async16(void* lds, const void* g) {
    __builtin_amdgcn_global_load_lds(
        (const __attribute__((address_space(1))) unsigned int*)g,
        (__attribute__((address_space(3))) unsigned int*)lds,
        16, 0, 0);
}

// ---------------- weight convert + transpose: [K][N] fp32 -> [N][K] bf16 ----
__global__ __launch_bounds__(256) void convert_transpose_kernel(
    const float* __restrict__ w1, const float* __restrict__ w2,
    unsigned short* __restrict__ w1T, unsigned short* __restrict__ w2T) {
    __shared__ float tile[64][68];
    int z = blockIdx.z; // 0..7 -> w1 experts, 8..15 -> w2 experts
    const float* src = (z < 8) ? (w1 + (size_t)z * IN_DIM * OUT_DIM)
                               : (w2 + (size_t)(z - 8) * OUT_DIM * OUT_DIM);
    unsigned short* dst = (z < 8) ? (w1T + (size_t)z * IN_DIM * OUT_DIM)
                                  : (w2T + (size_t)(z - 8) * OUT_DIM * OUT_DIM);
    int kt = blockIdx.x * 64, nt = blockIdx.y * 64;
    int t = threadIdx.x;
    int r = t >> 2, cq = (t & 3) * 16;
#pragma unroll
    for (int q = 0; q < 4; ++q) {
        float4 v = *(const float4*)(src + (size_t)(kt + r) * 1024 + nt + cq + q * 4);
        tile[r][cq + q * 4 + 0] = v.x;
        tile[r][cq + q * 4 + 1] = v.y;
        tile[r][cq + q * 4 + 2] = v.z;
        tile[r][cq + q * 4 + 3] = v.w;
    }
    __syncthreads();
    int n = t >> 2, kq = (t & 3) * 16;
#pragma unroll
    for (int q = 0; q < 4; ++q) {
        ushort4 o;
        o.x = f2bf(tile[kq + q * 4 + 0][n]);
        o.y = f2bf(tile[kq + q * 4 + 1][n]);
        o.z = f2bf(tile[kq + q * 4 + 2][n]);
        o.w = f2bf(tile[kq + q * 4 + 3][n]);
        *(ushort4*)(dst + (size_t)(nt + n) * 1024 + kt + kq + q * 4) = o;
    }
}

// ---------------- router: logits, top-2, softmax, x->bf16 -------------------
__global__ __launch_bounds__(256) void router_kernel(
    const float* __restrict__ x, const float* __restrict__ rw,
    const float* __restrict__ rb,
    unsigned short* __restrict__ xb,
    float* __restrict__ gating, int* __restrict__ enc,
    float2* __restrict__ gw) {
    __shared__ float srw[NE * IN_DIM]; // transposed: srw[e*1024 + k]
    int t = threadIdx.x;
#pragma unroll
    for (int i = 0; i < 4; ++i) {
        int k = t + i * 256;
        float4 a = *(const float4*)(rw + (size_t)k * NE);
        float4 b = *(const float4*)(rw + (size_t)k * NE + 4);
        srw[0 * IN_DIM + k] = a.x; srw[1 * IN_DIM + k] = a.y;
        srw[2 * IN_DIM + k] = a.z; srw[3 * IN_DIM + k] = a.w;
        srw[4 * IN_DIM + k] = b.x; srw[5 * IN_DIM + k] = b.y;
        srw[6 * IN_DIM + k] = b.z; srw[7 * IN_DIM + k] = b.w;
    }
    __syncthreads();
    int wave = t >> 6, lane = t & 63;
    int tok = blockIdx.x * 4 + wave;
    const float* xrow = x + (size_t)tok * IN_DIM;
    unsigned short* xbrow = xb + (size_t)tok * IN_DIM;
    float acc[NE] = {0, 0, 0, 0, 0, 0, 0, 0};
#pragma unroll
    for (int i = 0; i < 4; ++i) {
        int k = i * 256 + lane * 4;
        float4 xv = *(const float4*)(xrow + k);
        ushort4 o;
        o.x = f2bf(xv.x); o.y = f2bf(xv.y); o.z = f2bf(xv.z); o.w = f2bf(xv.w);
        *(ushort4*)(xbrow + k) = o;
#pragma unroll
        for (int e = 0; e < NE; ++e) {
            float4 wv = *(const float4*)(srw + e * IN_DIM + k);
            acc[e] = fmaf(xv.x, wv.x, fmaf(xv.y, wv.y, fmaf(xv.z, wv.z, fmaf(xv.w, wv.w, acc[e]))));
        }
    }
#pragma unroll
    for (int e = 0; e < NE; ++e) {
#pragma unroll
        for (int off = 32; off > 0; off >>= 1) acc[e] += __shfl_xor(acc[e], off);
        acc[e] += rb[e];
    }
    // top-2 (lowest index wins ties, matching lax.top_k)
    int e0 = 0; float v0 = acc[0];
#pragma unroll
    for (int e = 1; e < NE; ++e) if (acc[e] > v0) { v0 = acc[e]; e0 = e; }
    int e1 = -1; float v1 = -3.4e38f;
#pragma unroll
    for (int e = 0; e < NE; ++e) if (e != e0 && acc[e] > v1) { v1 = acc[e]; e1 = e; }
    float tg = __expf(v1 - v0);
    float inv = 1.0f / (1.0f + tg);
    float g0 = inv, g1 = tg * inv;
    if (lane < NE) gating[(size_t)tok * NE + lane] = (lane == e0) ? g0 : ((lane == e1) ? g1 : 0.0f);
    if (lane == 0) {
        enc[tok] = e0 | (e1 << 8);
        gw[tok] = make_float2(g0, g1);
    }
}

// ---------------- bucket: deterministic per-expert compaction, no atomics ---
// 1024 threads: 8 serial chunks instead of 32.
// slots[2*tok+which] = (e<<13) | local_idx.
__global__ __launch_bounds__(1024) void bucket_kernel(
    const int* __restrict__ enc,
    int* __restrict__ bidx, int* __restrict__ slots, int* __restrict__ cnt) {
    int e = blockIdx.x;
    __shared__ int wsum[16];
    __shared__ int runbase;
    int t = threadIdx.x, wave = t >> 6, lane = t & 63;
    if (t == 0) runbase = 0;
    __syncthreads();
    for (int c0 = 0; c0 < NTOK; c0 += 1024) {
        int tok = c0 + t;
        int v = enc[tok];
        int e0 = v & 0xff, e1 = (v >> 8) & 0xff;
        bool sel = (e0 == e) || (e1 == e);
        unsigned long long m = __ballot(sel);
        int pos = __popcll(m & ((1ull << lane) - 1ull));
        if (lane == 0) wsum[wave] = __popcll(m);
        __syncthreads();
        int wb = runbase;
        for (int w = 0; w < wave; ++w) wb += wsum[w];
        if (sel) {
            int p = wb + pos;
            bidx[e * NTOK + p] = tok;
            int which = (e0 == e) ? 0 : 1;
            slots[2 * tok + which] = (e << 13) | p;
        }
        __syncthreads();
        if (t == 0) {
            int s = 0;
#pragma unroll
            for (int w = 0; w < 16; ++w) s += wsum[w];
            runbase += s;
        }
        __syncthreads();
    }
    if (t == 0) cnt[e] = runbase;
}

// inline 8-entry exclusive prefix of cnt up to e (uniform scalar loads)
__device__ __forceinline__ int prefix_cnt(const int* __restrict__ cnt, int e) {
    int s = 0;
    for (int i = 0; i < NE; ++i) s += (i < e) ? cnt[i] : 0;
    return s;
}

// ---------------- GEMM1: H = relu(gather(Xb) @ W1 + b1), bf16 out ----------
// grid = (nt=8, mt=64, e=8): nt-fastest for A-row L2 sharing.
// Ping-pong LDS: 1 barrier/iter, loads for k+1 in flight across compute(k).
__global__ __launch_bounds__(256) void gemm1_kernel(
    const unsigned short* __restrict__ xb, const unsigned short* __restrict__ w1T,
    const float* __restrict__ b1, const int* __restrict__ bidx,
    const int* __restrict__ cnt,
    unsigned short* __restrict__ H) {
    int e = blockIdx.z;
    int n_e = cnt[e];
    int mt = blockIdx.y;
    if (mt * 128 >= n_e) return;
    int nt = blockIdx.x;
    __shared__ __attribute__((aligned(16))) unsigned short As[2][128 * 64];
    __shared__ __attribute__((aligned(16))) unsigned short Bs[2][128 * 64];
    int t = threadIdx.x, wave = t >> 6, lane = t & 63;
    const int* be = bidx + e * NTOK;
    const unsigned short* agp[4]; const unsigned short* bgp[4];
    int ldsoff[4];
#pragma unroll
    for (int is = 0; is < 4; ++is) {
        int c = is * 256 + t;
        int row = c >> 3;
        int colg = ((c & 7) ^ (row & 7)) * 8; // XOR swizzle (elements)
        int gr = mt * 128 + row;
        int grc = gr < n_e ? gr : n_e - 1;
        agp[is] = xb + (size_t)be[grc] * IN_DIM + colg;
        bgp[is] = w1T + ((size_t)e * OUT_DIM + nt * 128 + row) * IN_DIM + colg;
        ldsoff[is] = (is * 256 + wave * 64) * 8;
    }
    int wm = wave & 1, wn = wave >> 1;
    int quad = lane >> 4, l15 = lane & 15, sw = l15 & 7;
    f32x4 zero4 = {0.f, 0.f, 0.f, 0.f};
    f32x4 acc[4][4];
#pragma unroll
    for (int i = 0; i < 4; ++i)
#pragma unroll
        for (int j = 0; j < 4; ++j) acc[i][j] = zero4;

    // prologue: stage k-tile 0 into buffer 0
#pragma unroll
    for (int is = 0; is < 4; ++is) {
        async16(&As[0][ldsoff[is]], agp[is]);
        async16(&Bs[0][ldsoff[is]], bgp[is]);
    }
    for (int it = 0; it < 16; ++it) {
        __syncthreads(); // drains this wave's loads; all waves' tiles ready
        int buf = it & 1;
        if (it + 1 < 16) {
            int ktn = (it + 1) * 64;
#pragma unroll
            for (int is = 0; is < 4; ++is) {
                async16(&As[buf ^ 1][ldsoff[is]], agp[is] + ktn);
                async16(&Bs[buf ^ 1][ldsoff[is]], bgp[is] + ktn);
            }
        }
        const unsigned short* Ab = As[buf];
        const unsigned short* Bb = Bs[buf];
#pragma unroll
        for (int s = 0; s < 2; ++s) {
            int cidx = s * 4 + quad;
            bf16x8 av[4], bv[4];
#pragma unroll
            for (int i = 0; i < 4; ++i) {
                int m = wm * 64 + i * 16 + l15;
                av[i] = *(const bf16x8*)(Ab + m * 64 + ((cidx ^ sw) * 8));
            }
#pragma unroll
            for (int j = 0; j < 4; ++j) {
                int n = wn * 64 + j * 16 + l15;
                bv[j] = *(const bf16x8*)(Bb + n * 64 + ((cidx ^ sw) * 8));
            }
#pragma unroll
            for (int i = 0; i < 4; ++i)
#pragma unroll
                for (int j = 0; j < 4; ++j)
                    acc[i][j] = __builtin_amdgcn_mfma_f32_16x16x32_bf16(av[i], bv[j], acc[i][j], 0, 0, 0);
        }
    }
    // epilogue: + b1, relu, bf16 store to packed H
    int hbase = prefix_cnt(cnt, e);
    const float* b1e = b1 + (size_t)e * OUT_DIM;
    int n0 = nt * 128 + wn * 64 + l15;
#pragma unroll
    for (int j = 0; j < 4; ++j) {
        int n = n0 + j * 16;
        float bias = b1e[n];
#pragma unroll
        for (int i = 0; i < 4; ++i) {
            int m0 = mt * 128 + wm * 64 + i * 16 + quad * 4;
#pragma unroll
            for (int r = 0; r < 4; ++r) {
                int gm = m0 + r;
                if (gm < n_e) {
                    float h = acc[i][j][r] + bias;
                    h = h > 0.f ? h : 0.f;
                    H[(size_t)(hbase + gm) * OUT_DIM + n] = f2bf(h);
                }
            }
        }
    }
}

// ---------------- GEMM2: Y = H @ W2 (packed bf16, plain stores) -------------
__global__ __launch_bounds__(256) void gemm2_kernel(
    const unsigned short* __restrict__ H, const unsigned short* __restrict__ w2T,
    const int* __restrict__ cnt,
    unsigned short* __restrict__ Y) {
    int e = blockIdx.z;
    int n_e = cnt[e];
    int mt = blockIdx.y;
    if (mt * 128 >= n_e) return;
    int nt = blockIdx.x;
    __shared__ __attribute__((aligned(16))) unsigned short As[2][128 * 64];
    __shared__ __attribute__((aligned(16))) unsigned short Bs[2][128 * 64];
    int t = threadIdx.x, wave = t >> 6, lane = t & 63;
    int hbase = prefix_cnt(cnt, e);
    const unsigned short* agp[4]; const unsigned short* bgp[4];
    int ldsoff[4];
#pragma unroll
    for (int is = 0; is < 4; ++is) {
        int c = is * 256 + t;
        int row = c >> 3;
        int colg = ((c & 7) ^ (row & 7)) * 8;
        int gr = mt * 128 + row;
        int grc = gr < n_e ? gr : n_e - 1;
        agp[is] = H + (size_t)(hbase + grc) * OUT_DIM + colg;
        bgp[is] = w2T + ((size_t)e * OUT_DIM + nt * 128 + row) * OUT_DIM + colg;
        ldsoff[is] = (is * 256 + wave * 64) * 8;
    }
    int wm = wave & 1, wn = wave >> 1;
    int quad = lane >> 4, l15 = lane & 15, sw = l15 & 7;
    f32x4 zero4 = {0.f, 0.f, 0.f, 0.f};
    f32x4 acc[4][4];
#pragma unroll
    for (int i = 0; i < 4; ++i)
#pragma unroll
        for (int j = 0; j < 4; ++j) acc[i][j] = zero4;

#pragma unroll
    for (int is = 0; is < 4; ++is) {
        async16(&As[0][ldsoff[is]], agp[is]);
        async16(&Bs[0][ldsoff[is]], bgp[is]);
    }
    for (int it = 0; it < 16; ++it) {
        __syncthreads();
        int buf = it & 1;
        if (it + 1 < 16) {
            int ktn = (it + 1) * 64;
#pragma unroll
            for (int is = 0; is < 4; ++is) {
                async16(&As[buf ^ 1][ldsoff[is]], agp[is] + ktn);
                async16(&Bs[buf ^ 1][ldsoff[is]], bgp[is] + ktn);
            }
        }
        const unsigned short* Ab = As[buf];
        const unsigned short* Bb = Bs[buf];
#pragma unroll
        for (int s = 0; s < 2; ++s) {
            int cidx = s * 4 + quad;
            bf16x8 av[4], bv[4];
#pragma unroll
            for (int i = 0; i < 4; ++i) {
                int m = wm * 64 + i * 16 + l15;
                av[i] = *(const bf16x8*)(Ab + m * 64 + ((cidx ^ sw) * 8));
            }
#pragma unroll
            for (int j = 0; j < 4; ++j) {
                int n = wn * 64 + j * 16 + l15;
                bv[j] = *(const bf16x8*)(Bb + n * 64 + ((cidx ^ sw) * 8));
            }
#pragma unroll
            for (int i = 0; i < 4; ++i)
#pragma unroll
                for (int j = 0; j < 4; ++j)
                    acc[i][j] = __builtin_amdgcn_mfma_f32_16x16x32_bf16(av[i], bv[j], acc[i][j], 0, 0, 0);
        }
    }
    // epilogue: plain bf16 stores to packed Y
    int n0 = nt * 128 + wn * 64 + l15;
#pragma unroll
    for (int i = 0; i < 4; ++i) {
        int m0 = mt * 128 + wm * 64 + i * 16 + quad * 4;
#pragma unroll
        for (int r = 0; r < 4; ++r) {
            int gm = m0 + r;
            if (gm < n_e) {
                unsigned short* yrow = Y + (size_t)(hbase + gm) * OUT_DIM;
#pragma unroll
                for (int j = 0; j < 4; ++j)
                    yrow[n0 + j * 16] = f2bf(acc[i][j][r]);
            }
        }
    }
}

// ---------------- combine: out[tok] = g0*(Y[r0]+b2[e0]) + g1*(Y[r1]+b2[e1]) -
__global__ __launch_bounds__(256) void combine_kernel(
    const unsigned short* __restrict__ Y, const float* __restrict__ b2,
    const float2* __restrict__ gw, const int* __restrict__ slots,
    const int* __restrict__ cnt, float* __restrict__ out) {
    int t = threadIdx.x, wave = t >> 6, lane = t & 63;
    int tok = blockIdx.x * 4 + wave;
    int pre[NE];
    {
        int s = 0;
#pragma unroll
        for (int i = 0; i < NE; ++i) { pre[i] = s; s += cnt[i]; }
    }
    int s0 = slots[2 * tok], s1 = slots[2 * tok + 1];
    int e0 = s0 >> 13, e1 = s1 >> 13;
    int r0 = pre[e0] + (s0 & 8191);
    int r1 = pre[e1] + (s1 & 8191);
    float2 g = gw[tok];
    const unsigned short* y0 = Y + (size_t)r0 * OUT_DIM;
    const unsigned short* y1 = Y + (size_t)r1 * OUT_DIM;
    const float* c0 = b2 + (size_t)e0 * OUT_DIM;
    const float* c1 = b2 + (size_t)e1 * OUT_DIM;
    float* orow = out + (size_t)tok * OUT_DIM;
#pragma unroll
    for (int i = 0; i < 2; ++i) {
        int c = i * 512 + lane * 8;
        uint4 ua = *(const uint4*)(y0 + c);
        uint4 ub = *(const uint4*)(y1 + c);
        float a[8], b[8];
        bf2x(ua.x, a[0], a[1]); bf2x(ua.y, a[2], a[3]);
        bf2x(ua.z, a[4], a[5]); bf2x(ua.w, a[6], a[7]);
        bf2x(ub.x, b[0], b[1]); bf2x(ub.y, b[2], b[3]);
        bf2x(ub.z, b[4], b[5]); bf2x(ub.w, b[6], b[7]);
        float4 p0 = *(const float4*)(c0 + c);
        float4 p1 = *(const float4*)(c0 + c + 4);
        float4 q0 = *(const float4*)(c1 + c);
        float4 q1 = *(const float4*)(c1 + c + 4);
        float o[8];
        o[0] = g.x * (a[0] + p0.x) + g.y * (b[0] + q0.x);
        o[1] = g.x * (a[1] + p0.y) + g.y * (b[1] + q0.y);
        o[2] = g.x * (a[2] + p0.z) + g.y * (b[2] + q0.z);
        o[3] = g.x * (a[3] + p0.w) + g.y * (b[3] + q0.w);
        o[4] = g.x * (a[4] + p1.x) + g.y * (b[4] + q1.x);
        o[5] = g.x * (a[5] + p1.y) + g.y * (b[5] + q1.y);
        o[6] = g.x * (a[6] + p1.z) + g.y * (b[6] + q1.z);
        o[7] = g.x * (a[7] + p1.w) + g.y * (b[7] + q1.w);
        *(float4*)(orow + c) = make_float4(o[0], o[1], o[2], o[3]);
        *(float4*)(orow + c + 4) = make_float4(o[4], o[5], o[6], o[7]);
    }
}

extern "C" void kernel_launch(void* const* d_in, const int* in_sizes, int n_in,
                              void* d_out, int out_size, void* d_ws, size_t ws_size,
                              hipStream_t stream) {
    const float* x  = (const float*)d_in[0];
    const float* rw = (const float*)d_in[1];
    const float* rb = (const float*)d_in[2];
    const float* w1 = (const float*)d_in[3];
    const float* b1 = (const float*)d_in[4];
    const float* w2 = (const float*)d_in[5];
    const float* b2 = (const float*)d_in[6];
    float* out = (float*)d_out;                       // fused [8192,1024]
    float* gating = out + (size_t)NTOK * OUT_DIM;     // gating [8192,8]

    char* ws = (char*)d_ws;
    // ws layout (bytes). Y reuses [0,32MiB): xb+w1T dead after gemm1
    // (stream-ordered). enc/gw outside H region.
    unsigned short* xb  = (unsigned short*)(ws + 0);          // 16 MiB
    unsigned short* Y   = (unsigned short*)(ws + 0);          // 32 MiB (gemm2+)
    unsigned short* w1T = (unsigned short*)(ws + 16777216);   // 16 MiB
    unsigned short* w2T = (unsigned short*)(ws + 33554432);   // 16 MiB
    unsigned short* H   = (unsigned short*)(ws + 50331648);   // 32 MiB
    int*   bidx  = (int*)(ws + 83886080);                     // 256 KiB
    int*   slots = (int*)(ws + 84148224);                     // 64 KiB
    int*   cnt   = (int*)(ws + 84213760);                     // 64 B
    int*    enc  = (int*)(ws + 84213888);                     // 32 KiB
    float2* gw   = (float2*)(ws + 84246656);                  // 64 KiB

    convert_transpose_kernel<<<dim3(16, 16, 16), 256, 0, stream>>>(w1, w2, w1T, w2T);
    router_kernel<<<NTOK / 4, 256, 0, stream>>>(x, rw, rb, xb, gating, enc, gw);
    bucket_kernel<<<NE, 1024, 0, stream>>>(enc, bidx, slots, cnt);
    gemm1_kernel<<<dim3(8, 64, 8), 256, 0, stream>>>(xb, w1T, b1, bidx, cnt, H);
    gemm2_kernel<<<dim3(8, 64, 8), 256, 0, stream>>>(H, w2T, cnt, Y);
    combine_kernel<<<NTOK / 4, 256, 0, stream>>>(Y, b2, gw, slots, cnt, out);
    (void)in_sizes; (void)n_in; (void)out_size; (void)ws_size;
}

// Round 5
// 317.263 us; speedup vs baseline: 1.7371x; 1.0278x over previous
//
#include <hip/hip_runtime.h>
#include <hip/hip_bf16.h>
#include <cstdint>
#include <cstddef>

#define IN_DIM 1024
#define OUT_DIM 1024
#define NE 8
#define NTOK 8192

typedef __bf16 bf16x8 __attribute__((ext_vector_type(8)));
typedef float f32x4 __attribute__((ext_vector_type(4)));

// RNE float -> bf16 bits
__device__ __forceinline__ unsigned short f2bf(float f) {
    unsigned u = __float_as_uint(f);
    unsigned r = 0x7fffu + ((u >> 16) & 1u);
    return (unsigned short)((u + r) >> 16);
}

// decode packed bf16 pair (u32) -> two floats
__device__ __forceinline__ void bf2x(unsigned u, float& lo, float& hi) {
    lo = __uint_as_float(u << 16);
    hi = __uint_as_float(u & 0xffff0000u);
}

// async global->LDS, 16B per lane. lds must be wave-uniform base; g is per-lane.
__device__ __forceinline__ void async16(void* lds, const void* g) {
    __builtin_amdgcn_global_load_lds(
        (const __attribute__((address_space(1))) unsigned int*)g,
        (__attribute__((address_space(3))) unsigned int*)lds,
        16, 0, 0);
}

// ---------------- weight convert + transpose: [K][N] fp32 -> [N][K] bf16 ----
__global__ __launch_bounds__(256) void convert_transpose_kernel(
    const float* __restrict__ w1, const float* __restrict__ w2,
    unsigned short* __restrict__ w1T, unsigned short* __restrict__ w2T) {
    __shared__ float tile[64][68];
    int z = blockIdx.z; // 0..7 -> w1 experts, 8..15 -> w2 experts
    const float* src = (z < 8) ? (w1 + (size_t)z * IN_DIM * OUT_DIM)
                               : (w2 + (size_t)(z - 8) * OUT_DIM * OUT_DIM);
    unsigned short* dst = (z < 8) ? (w1T + (size_t)z * IN_DIM * OUT_DIM)
                                  : (w2T + (size_t)(z - 8) * OUT_DIM * OUT_DIM);
    int kt = blockIdx.x * 64, nt = blockIdx.y * 64;
    int t = threadIdx.x;
    int r = t >> 2, cq = (t & 3) * 16;
#pragma unroll
    for (int q = 0; q < 4; ++q) {
        float4 v = *(const float4*)(src + (size_t)(kt + r) * 1024 + nt + cq + q * 4);
        tile[r][cq + q * 4 + 0] = v.x;
        tile[r][cq + q * 4 + 1] = v.y;
        tile[r][cq + q * 4 + 2] = v.z;
        tile[r][cq + q * 4 + 3] = v.w;
    }
    __syncthreads();
    int n = t >> 2, kq = (t & 3) * 16;
#pragma unroll
    for (int q = 0; q < 4; ++q) {
        ushort4 o;
        o.x = f2bf(tile[kq + q * 4 + 0][n]);
        o.y = f2bf(tile[kq + q * 4 + 1][n]);
        o.z = f2bf(tile[kq + q * 4 + 2][n]);
        o.w = f2bf(tile[kq + q * 4 + 3][n]);
        *(ushort4*)(dst + (size_t)(nt + n) * 1024 + kt + kq + q * 4) = o;
    }
}

// ---------------- router: logits, top-2, softmax, x->bf16 -------------------
__global__ __launch_bounds__(256) void router_kernel(
    const float* __restrict__ x, const float* __restrict__ rw,
    const float* __restrict__ rb,
    unsigned short* __restrict__ xb,
    float* __restrict__ gating, int* __restrict__ enc,
    float2* __restrict__ gw) {
    __shared__ float srw[NE * IN_DIM]; // transposed: srw[e*1024 + k]
    int t = threadIdx.x;
#pragma unroll
    for (int i = 0; i < 4; ++i) {
        int k = t + i * 256;
        float4 a = *(const float4*)(rw + (size_t)k * NE);
        float4 b = *(const float4*)(rw + (size_t)k * NE + 4);
        srw[0 * IN_DIM + k] = a.x; srw[1 * IN_DIM + k] = a.y;
        srw[2 * IN_DIM + k] = a.z; srw[3 * IN_DIM + k] = a.w;
        srw[4 * IN_DIM + k] = b.x; srw[5 * IN_DIM + k] = b.y;
        srw[6 * IN_DIM + k] = b.z; srw[7 * IN_DIM + k] = b.w;
    }
    __syncthreads();
    int wave = t >> 6, lane = t & 63;
    int tok = blockIdx.x * 4 + wave;
    const float* xrow = x + (size_t)tok * IN_DIM;
    unsigned short* xbrow = xb + (size_t)tok * IN_DIM;
    float acc[NE] = {0, 0, 0, 0, 0, 0, 0, 0};
#pragma unroll
    for (int i = 0; i < 4; ++i) {
        int k = i * 256 + lane * 4;
        float4 xv = *(const float4*)(xrow + k);
        ushort4 o;
        o.x = f2bf(xv.x); o.y = f2bf(xv.y); o.z = f2bf(xv.z); o.w = f2bf(xv.w);
        *(ushort4*)(xbrow + k) = o;
#pragma unroll
        for (int e = 0; e < NE; ++e) {
            float4 wv = *(const float4*)(srw + e * IN_DIM + k);
            acc[e] = fmaf(xv.x, wv.x, fmaf(xv.y, wv.y, fmaf(xv.z, wv.z, fmaf(xv.w, wv.w, acc[e]))));
        }
    }
#pragma unroll
    for (int e = 0; e < NE; ++e) {
#pragma unroll
        for (int off = 32; off > 0; off >>= 1) acc[e] += __shfl_xor(acc[e], off);
        acc[e] += rb[e];
    }
    // top-2 (lowest index wins ties, matching lax.top_k)
    int e0 = 0; float v0 = acc[0];
#pragma unroll
    for (int e = 1; e < NE; ++e) if (acc[e] > v0) { v0 = acc[e]; e0 = e; }
    int e1 = -1; float v1 = -3.4e38f;
#pragma unroll
    for (int e = 0; e < NE; ++e) if (e != e0 && acc[e] > v1) { v1 = acc[e]; e1 = e; }
    float tg = __expf(v1 - v0);
    float inv = 1.0f / (1.0f + tg);
    float g0 = inv, g1 = tg * inv;
    if (lane < NE) gating[(size_t)tok * NE + lane] = (lane == e0) ? g0 : ((lane == e1) ? g1 : 0.0f);
    if (lane == 0) {
        enc[tok] = e0 | (e1 << 8);
        gw[tok] = make_float2(g0, g1);
    }
}

// ---------------- bucket: deterministic per-expert compaction, no atomics ---
// slots[2*tok+which] = (e<<13) | local_idx.
__global__ __launch_bounds__(1024) void bucket_kernel(
    const int* __restrict__ enc,
    int* __restrict__ bidx, int* __restrict__ slots, int* __restrict__ cnt) {
    int e = blockIdx.x;
    __shared__ int wsum[16];
    __shared__ int runbase;
    int t = threadIdx.x, wave = t >> 6, lane = t & 63;
    if (t == 0) runbase = 0;
    __syncthreads();
    for (int c0 = 0; c0 < NTOK; c0 += 1024) {
        int tok = c0 + t;
        int v = enc[tok];
        int e0 = v & 0xff, e1 = (v >> 8) & 0xff;
        bool sel = (e0 == e) || (e1 == e);
        unsigned long long m = __ballot(sel);
        int pos = __popcll(m & ((1ull << lane) - 1ull));
        if (lane == 0) wsum[wave] = __popcll(m);
        __syncthreads();
        int wb = runbase;
        for (int w = 0; w < wave; ++w) wb += wsum[w];
        if (sel) {
            int p = wb + pos;
            bidx[e * NTOK + p] = tok;
            int which = (e0 == e) ? 0 : 1;
            slots[2 * tok + which] = (e << 13) | p;
        }
        __syncthreads();
        if (t == 0) {
            int s = 0;
#pragma unroll
            for (int w = 0; w < 16; ++w) s += wsum[w];
            runbase += s;
        }
        __syncthreads();
    }
    if (t == 0) cnt[e] = runbase;
}

// inline 8-entry exclusive prefix of cnt up to e (uniform scalar loads)
__device__ __forceinline__ int prefix_cnt(const int* __restrict__ cnt, int e) {
    int s = 0;
    for (int i = 0; i < NE; ++i) s += (i < e) ? cnt[i] : 0;
    return s;
}

// ---------------- GEMM1: H = relu(gather(Xb) @ W1 + b1), bf16 out ----------
// 1D grid, XCD-aware: e = b&7 pins each expert's blocks to one XCD (round-
// robin heuristic) so the expert's B-slice (2 MiB) is L2-resident and its
// gathered A rows get 8-way in-cache reuse. R4 post-mortem: nt-fastest 3D
// grid spread same-A blocks over 8 XCDs -> FETCH 122 MB (A refetched per XCD).
__global__ __launch_bounds__(256) void gemm1_kernel(
    const unsigned short* __restrict__ xb, const unsigned short* __restrict__ w1T,
    const float* __restrict__ b1, const int* __restrict__ bidx,
    const int* __restrict__ cnt,
    unsigned short* __restrict__ H) {
    int b = blockIdx.x;
    int e = b & 7;
    int t2 = b >> 3;
    int nt = t2 & 7;
    int mt = t2 >> 3;
    int n_e = cnt[e];
    if (mt * 128 >= n_e) return;
    __shared__ __attribute__((aligned(16))) unsigned short As[2][128 * 64];
    __shared__ __attribute__((aligned(16))) unsigned short Bs[2][128 * 64];
    int t = threadIdx.x, wave = t >> 6, lane = t & 63;
    const int* be = bidx + e * NTOK;
    const unsigned short* agp[4]; const unsigned short* bgp[4];
    int ldsoff[4];
#pragma unroll
    for (int is = 0; is < 4; ++is) {
        int c = is * 256 + t;
        int row = c >> 3;
        int colg = ((c & 7) ^ (row & 7)) * 8; // XOR swizzle (elements)
        int gr = mt * 128 + row;
        int grc = gr < n_e ? gr : n_e - 1;
        agp[is] = xb + (size_t)be[grc] * IN_DIM + colg;
        bgp[is] = w1T + ((size_t)e * OUT_DIM + nt * 128 + row) * IN_DIM + colg;
        ldsoff[is] = (is * 256 + wave * 64) * 8;
    }
    int wm = wave & 1, wn = wave >> 1;
    int quad = lane >> 4, l15 = lane & 15, sw = l15 & 7;
    f32x4 zero4 = {0.f, 0.f, 0.f, 0.f};
    f32x4 acc[4][4];
#pragma unroll
    for (int i = 0; i < 4; ++i)
#pragma unroll
        for (int j = 0; j < 4; ++j) acc[i][j] = zero4;

    // prologue: stage k-tile 0 into buffer 0
#pragma unroll
    for (int is = 0; is < 4; ++is) {
        async16(&As[0][ldsoff[is]], agp[is]);
        async16(&Bs[0][ldsoff[is]], bgp[is]);
    }
    for (int it = 0; it < 16; ++it) {
        __syncthreads();
        int buf = it & 1;
        if (it + 1 < 16) {
            int ktn = (it + 1) * 64;
#pragma unroll
            for (int is = 0; is < 4; ++is) {
                async16(&As[buf ^ 1][ldsoff[is]], agp[is] + ktn);
                async16(&Bs[buf ^ 1][ldsoff[is]], bgp[is] + ktn);
            }
        }
        const unsigned short* Ab = As[buf];
        const unsigned short* Bb = Bs[buf];
#pragma unroll
        for (int s = 0; s < 2; ++s) {
            int cidx = s * 4 + quad;
            bf16x8 av[4], bv[4];
#pragma unroll
            for (int i = 0; i < 4; ++i) {
                int m = wm * 64 + i * 16 + l15;
                av[i] = *(const bf16x8*)(Ab + m * 64 + ((cidx ^ sw) * 8));
            }
#pragma unroll
            for (int j = 0; j < 4; ++j) {
                int n = wn * 64 + j * 16 + l15;
                bv[j] = *(const bf16x8*)(Bb + n * 64 + ((cidx ^ sw) * 8));
            }
#pragma unroll
            for (int i = 0; i < 4; ++i)
#pragma unroll
                for (int j = 0; j < 4; ++j)
                    acc[i][j] = __builtin_amdgcn_mfma_f32_16x16x32_bf16(av[i], bv[j], acc[i][j], 0, 0, 0);
        }
    }
    // epilogue: + b1, relu, bf16 store to packed H
    int hbase = prefix_cnt(cnt, e);
    const float* b1e = b1 + (size_t)e * OUT_DIM;
    int n0 = nt * 128 + wn * 64 + l15;
#pragma unroll
    for (int j = 0; j < 4; ++j) {
        int n = n0 + j * 16;
        float bias = b1e[n];
#pragma unroll
        for (int i = 0; i < 4; ++i) {
            int m0 = mt * 128 + wm * 64 + i * 16 + quad * 4;
#pragma unroll
            for (int r = 0; r < 4; ++r) {
                int gm = m0 + r;
                if (gm < n_e) {
                    float h = acc[i][j][r] + bias;
                    h = h > 0.f ? h : 0.f;
                    H[(size_t)(hbase + gm) * OUT_DIM + n] = f2bf(h);
                }
            }
        }
    }
}

// ---------------- GEMM2: Y = H @ W2 (packed bf16, plain stores) -------------
__global__ __launch_bounds__(256) void gemm2_kernel(
    const unsigned short* __restrict__ H, const unsigned short* __restrict__ w2T,
    const int* __restrict__ cnt,
    unsigned short* __restrict__ Y) {
    int b = blockIdx.x;
    int e = b & 7;
    int t2 = b >> 3;
    int nt = t2 & 7;
    int mt = t2 >> 3;
    int n_e = cnt[e];
    if (mt * 128 >= n_e) return;
    __shared__ __attribute__((aligned(16))) unsigned short As[2][128 * 64];
    __shared__ __attribute__((aligned(16))) unsigned short Bs[2][128 * 64];
    int t = threadIdx.x, wave = t >> 6, lane = t & 63;
    int hbase = prefix_cnt(cnt, e);
    const unsigned short* agp[4]; const unsigned short* bgp[4];
    int ldsoff[4];
#pragma unroll
    for (int is = 0; is < 4; ++is) {
        int c = is * 256 + t;
        int row = c >> 3;
        int colg = ((c & 7) ^ (row & 7)) * 8;
        int gr = mt * 128 + row;
        int grc = gr < n_e ? gr : n_e - 1;
        agp[is] = H + (size_t)(hbase + grc) * OUT_DIM + colg;
        bgp[is] = w2T + ((size_t)e * OUT_DIM + nt * 128 + row) * OUT_DIM + colg;
        ldsoff[is] = (is * 256 + wave * 64) * 8;
    }
    int wm = wave & 1, wn = wave >> 1;
    int quad = lane >> 4, l15 = lane & 15, sw = l15 & 7;
    f32x4 zero4 = {0.f, 0.f, 0.f, 0.f};
    f32x4 acc[4][4];
#pragma unroll
    for (int i = 0; i < 4; ++i)
#pragma unroll
        for (int j = 0; j < 4; ++j) acc[i][j] = zero4;

#pragma unroll
    for (int is = 0; is < 4; ++is) {
        async16(&As[0][ldsoff[is]], agp[is]);
        async16(&Bs[0][ldsoff[is]], bgp[is]);
    }
    for (int it = 0; it < 16; ++it) {
        __syncthreads();
        int buf = it & 1;
        if (it + 1 < 16) {
            int ktn = (it + 1) * 64;
#pragma unroll
            for (int is = 0; is < 4; ++is) {
                async16(&As[buf ^ 1][ldsoff[is]], agp[is] + ktn);
                async16(&Bs[buf ^ 1][ldsoff[is]], bgp[is] + ktn);
            }
        }
        const unsigned short* Ab = As[buf];
        const unsigned short* Bb = Bs[buf];
#pragma unroll
        for (int s = 0; s < 2; ++s) {
            int cidx = s * 4 + quad;
            bf16x8 av[4], bv[4];
#pragma unroll
            for (int i = 0; i < 4; ++i) {
                int m = wm * 64 + i * 16 + l15;
                av[i] = *(const bf16x8*)(Ab + m * 64 + ((cidx ^ sw) * 8));
            }
#pragma unroll
            for (int j = 0; j < 4; ++j) {
                int n = wn * 64 + j * 16 + l15;
                bv[j] = *(const bf16x8*)(Bb + n * 64 + ((cidx ^ sw) * 8));
            }
#pragma unroll
            for (int i = 0; i < 4; ++i)
#pragma unroll
                for (int j = 0; j < 4; ++j)
                    acc[i][j] = __builtin_amdgcn_mfma_f32_16x16x32_bf16(av[i], bv[j], acc[i][j], 0, 0, 0);
        }
    }
    // epilogue: plain bf16 stores to packed Y
    int n0 = nt * 128 + wn * 64 + l15;
#pragma unroll
    for (int i = 0; i < 4; ++i) {
        int m0 = mt * 128 + wm * 64 + i * 16 + quad * 4;
#pragma unroll
        for (int r = 0; r < 4; ++r) {
            int gm = m0 + r;
            if (gm < n_e) {
                unsigned short* yrow = Y + (size_t)(hbase + gm) * OUT_DIM;
#pragma unroll
                for (int j = 0; j < 4; ++j)
                    yrow[n0 + j * 16] = f2bf(acc[i][j][r]);
            }
        }
    }
}

// ---------------- combine: out[tok] = g0*(Y[r0]+b2[e0]) + g1*(Y[r1]+b2[e1]) -
__global__ __launch_bounds__(256) void combine_kernel(
    const unsigned short* __restrict__ Y, const float* __restrict__ b2,
    const float2* __restrict__ gw, const int* __restrict__ slots,
    const int* __restrict__ cnt, float* __restrict__ out) {
    int t = threadIdx.x, wave = t >> 6, lane = t & 63;
    int tok = blockIdx.x * 4 + wave;
    int pre[NE];
    {
        int s = 0;
#pragma unroll
        for (int i = 0; i < NE; ++i) { pre[i] = s; s += cnt[i]; }
    }
    int s0 = slots[2 * tok], s1 = slots[2 * tok + 1];
    int e0 = s0 >> 13, e1 = s1 >> 13;
    int r0 = pre[e0] + (s0 & 8191);
    int r1 = pre[e1] + (s1 & 8191);
    float2 g = gw[tok];
    const unsigned short* y0 = Y + (size_t)r0 * OUT_DIM;
    const unsigned short* y1 = Y + (size_t)r1 * OUT_DIM;
    const float* c0 = b2 + (size_t)e0 * OUT_DIM;
    const float* c1 = b2 + (size_t)e1 * OUT_DIM;
    float* orow = out + (size_t)tok * OUT_DIM;
#pragma unroll
    for (int i = 0; i < 2; ++i) {
        int c = i * 512 + lane * 8;
        uint4 ua = *(const uint4*)(y0 + c);
        uint4 ub = *(const uint4*)(y1 + c);
        float a[8], b[8];
        bf2x(ua.x, a[0], a[1]); bf2x(ua.y, a[2], a[3]);
        bf2x(ua.z, a[4], a[5]); bf2x(ua.w, a[6], a[7]);
        bf2x(ub.x, b[0], b[1]); bf2x(ub.y, b[2], b[3]);
        bf2x(ub.z, b[4], b[5]); bf2x(ub.w, b[6], b[7]);
        float4 p0 = *(const float4*)(c0 + c);
        float4 p1 = *(const float4*)(c0 + c + 4);
        float4 q0 = *(const float4*)(c1 + c);
        float4 q1 = *(const float4*)(c1 + c + 4);
        float o[8];
        o[0] = g.x * (a[0] + p0.x) + g.y * (b[0] + q0.x);
        o[1] = g.x * (a[1] + p0.y) + g.y * (b[1] + q0.y);
        o[2] = g.x * (a[2] + p0.z) + g.y * (b[2] + q0.z);
        o[3] = g.x * (a[3] + p0.w) + g.y * (b[3] + q0.w);
        o[4] = g.x * (a[4] + p1.x) + g.y * (b[4] + q1.x);
        o[5] = g.x * (a[5] + p1.y) + g.y * (b[5] + q1.y);
        o[6] = g.x * (a[6] + p1.z) + g.y * (b[6] + q1.z);
        o[7] = g.x * (a[7] + p1.w) + g.y * (b[7] + q1.w);
        *(float4*)(orow + c) = make_float4(o[0], o[1], o[2], o[3]);
        *(float4*)(orow + c + 4) = make_float4(o[4], o[5], o[6], o[7]);
    }
}

extern "C" void kernel_launch(void* const* d_in, const int* in_sizes, int n_in,
                              void* d_out, int out_size, void* d_ws, size_t ws_size,
                              hipStream_t stream) {
    const float* x  = (const float*)d_in[0];
    const float* rw = (const float*)d_in[1];
    const float* rb = (const float*)d_in[2];
    const float* w1 = (const float*)d_in[3];
    const float* b1 = (const float*)d_in[4];
    const float* w2 = (const float*)d_in[5];
    const float* b2 = (const float*)d_in[6];
    float* out = (float*)d_out;                       // fused [8192,1024]
    float* gating = out + (size_t)NTOK * OUT_DIM;     // gating [8192,8]

    char* ws = (char*)d_ws;
    // ws layout (bytes). Y reuses [0,32MiB): xb+w1T dead after gemm1
    // (stream-ordered). enc/gw outside H region.
    unsigned short* xb  = (unsigned short*)(ws + 0);          // 16 MiB
    unsigned short* Y   = (unsigned short*)(ws + 0);          // 32 MiB (gemm2+)
    unsigned short* w1T = (unsigned short*)(ws + 16777216);   // 16 MiB
    unsigned short* w2T = (unsigned short*)(ws + 33554432);   // 16 MiB
    unsigned short* H   = (unsigned short*)(ws + 50331648);   // 32 MiB
    int*   bidx  = (int*)(ws + 83886080);                     // 256 KiB
    int*   slots = (int*)(ws + 84148224);                     // 64 KiB
    int*   cnt   = (int*)(ws + 84213760);                     // 64 B
    int*    enc  = (int*)(ws + 84213888);                     // 32 KiB
    float2* gw   = (float2*)(ws + 84246656);                  // 64 KiB

    convert_transpose_kernel<<<dim3(16, 16, 16), 256, 0, stream>>>(w1, w2, w1T, w2T);
    router_kernel<<<NTOK / 4, 256, 0, stream>>>(x, rw, rb, xb, gating, enc, gw);
    bucket_kernel<<<NE, 1024, 0, stream>>>(enc, bidx, slots, cnt);
    gemm1_kernel<<<8 * 8 * 64, 256, 0, stream>>>(xb, w1T, b1, bidx, cnt, H);
    gemm2_kernel<<<8 * 8 * 64, 256, 0, stream>>>(H, w2T, cnt, Y);
    combine_kernel<<<NTOK / 4, 256, 0, stream>>>(Y, b2, gw, slots, cnt, out);
    (void)in_sizes; (void)n_in; (void)out_size; (void)ws_size;
}

// Round 6
// 308.228 us; speedup vs baseline: 1.7880x; 1.0293x over previous
//
#include <hip/hip_runtime.h>
#include <hip/hip_bf16.h>
#include <cstdint>
#include <cstddef>

#define IN_DIM 1024
#define OUT_DIM 1024
#define NE 8
#define NTOK 8192

typedef __bf16 bf16x8 __attribute__((ext_vector_type(8)));
typedef float f32x4 __attribute__((ext_vector_type(4)));

// RNE float -> bf16 bits
__device__ __forceinline__ unsigned short f2bf(float f) {
    unsigned u = __float_as_uint(f);
    unsigned r = 0x7fffu + ((u >> 16) & 1u);
    return (unsigned short)((u + r) >> 16);
}

// decode packed bf16 pair (u32) -> two floats
__device__ __forceinline__ void bf2x(unsigned u, float& lo, float& hi) {
    lo = __uint_as_float(u << 16);
    hi = __uint_as_float(u & 0xffff0000u);
}

// async global->LDS, 16B per lane. lds must be wave-uniform base; g is per-lane.
__device__ __forceinline__ void async16(void* lds, const void* g) {
    __builtin_amdgcn_global_load_lds(
        (const __attribute__((address_space(1))) unsigned int*)g,
        (__attribute__((address_space(3))) unsigned int*)lds,
        16, 0, 0);
}

// ---------------- weight convert + transpose: [K][N] fp32 -> [N][K] bf16 ----
__global__ __launch_bounds__(256) void convert_transpose_kernel(
    const float* __restrict__ w1, const float* __restrict__ w2,
    unsigned short* __restrict__ w1T, unsigned short* __restrict__ w2T) {
    __shared__ float tile[64][68];
    int z = blockIdx.z; // 0..7 -> w1 experts, 8..15 -> w2 experts
    const float* src = (z < 8) ? (w1 + (size_t)z * IN_DIM * OUT_DIM)
                               : (w2 + (size_t)(z - 8) * OUT_DIM * OUT_DIM);
    unsigned short* dst = (z < 8) ? (w1T + (size_t)z * IN_DIM * OUT_DIM)
                                  : (w2T + (size_t)(z - 8) * OUT_DIM * OUT_DIM);
    int kt = blockIdx.x * 64, nt = blockIdx.y * 64;
    int t = threadIdx.x;
    int r = t >> 2, cq = (t & 3) * 16;
#pragma unroll
    for (int q = 0; q < 4; ++q) {
        float4 v = *(const float4*)(src + (size_t)(kt + r) * 1024 + nt + cq + q * 4);
        tile[r][cq + q * 4 + 0] = v.x;
        tile[r][cq + q * 4 + 1] = v.y;
        tile[r][cq + q * 4 + 2] = v.z;
        tile[r][cq + q * 4 + 3] = v.w;
    }
    __syncthreads();
    int n = t >> 2, kq = (t & 3) * 16;
#pragma unroll
    for (int q = 0; q < 4; ++q) {
        ushort4 o;
        o.x = f2bf(tile[kq + q * 4 + 0][n]);
        o.y = f2bf(tile[kq + q * 4 + 1][n]);
        o.z = f2bf(tile[kq + q * 4 + 2][n]);
        o.w = f2bf(tile[kq + q * 4 + 3][n]);
        *(ushort4*)(dst + (size_t)(nt + n) * 1024 + kt + kq + q * 4) = o;
    }
}

// ---------------- router: logits, top-2, softmax, x->bf16 -------------------
__global__ __launch_bounds__(256) void router_kernel(
    const float* __restrict__ x, const float* __restrict__ rw,
    const float* __restrict__ rb,
    unsigned short* __restrict__ xb,
    float* __restrict__ gating, int* __restrict__ enc,
    float2* __restrict__ gw) {
    __shared__ float srw[NE * IN_DIM]; // transposed: srw[e*1024 + k]
    int t = threadIdx.x;
#pragma unroll
    for (int i = 0; i < 4; ++i) {
        int k = t + i * 256;
        float4 a = *(const float4*)(rw + (size_t)k * NE);
        float4 b = *(const float4*)(rw + (size_t)k * NE + 4);
        srw[0 * IN_DIM + k] = a.x; srw[1 * IN_DIM + k] = a.y;
        srw[2 * IN_DIM + k] = a.z; srw[3 * IN_DIM + k] = a.w;
        srw[4 * IN_DIM + k] = b.x; srw[5 * IN_DIM + k] = b.y;
        srw[6 * IN_DIM + k] = b.z; srw[7 * IN_DIM + k] = b.w;
    }
    __syncthreads();
    int wave = t >> 6, lane = t & 63;
    int tok = blockIdx.x * 4 + wave;
    const float* xrow = x + (size_t)tok * IN_DIM;
    unsigned short* xbrow = xb + (size_t)tok * IN_DIM;
    float acc[NE] = {0, 0, 0, 0, 0, 0, 0, 0};
#pragma unroll
    for (int i = 0; i < 4; ++i) {
        int k = i * 256 + lane * 4;
        float4 xv = *(const float4*)(xrow + k);
        ushort4 o;
        o.x = f2bf(xv.x); o.y = f2bf(xv.y); o.z = f2bf(xv.z); o.w = f2bf(xv.w);
        *(ushort4*)(xbrow + k) = o;
#pragma unroll
        for (int e = 0; e < NE; ++e) {
            float4 wv = *(const float4*)(srw + e * IN_DIM + k);
            acc[e] = fmaf(xv.x, wv.x, fmaf(xv.y, wv.y, fmaf(xv.z, wv.z, fmaf(xv.w, wv.w, acc[e]))));
        }
    }
#pragma unroll
    for (int e = 0; e < NE; ++e) {
#pragma unroll
        for (int off = 32; off > 0; off >>= 1) acc[e] += __shfl_xor(acc[e], off);
        acc[e] += rb[e];
    }
    // top-2 (lowest index wins ties, matching lax.top_k)
    int e0 = 0; float v0 = acc[0];
#pragma unroll
    for (int e = 1; e < NE; ++e) if (acc[e] > v0) { v0 = acc[e]; e0 = e; }
    int e1 = -1; float v1 = -3.4e38f;
#pragma unroll
    for (int e = 0; e < NE; ++e) if (e != e0 && acc[e] > v1) { v1 = acc[e]; e1 = e; }
    float tg = __expf(v1 - v0);
    float inv = 1.0f / (1.0f + tg);
    float g0 = inv, g1 = tg * inv;
    if (lane < NE) gating[(size_t)tok * NE + lane] = (lane == e0) ? g0 : ((lane == e1) ? g1 : 0.0f);
    if (lane == 0) {
        enc[tok] = e0 | (e1 << 8);
        gw[tok] = make_float2(g0, g1);
    }
}

// ---------------- bucket: deterministic per-expert compaction, no atomics ---
// slots[2*tok+which] = (e<<13) | local_idx.
__global__ __launch_bounds__(1024) void bucket_kernel(
    const int* __restrict__ enc,
    int* __restrict__ bidx, int* __restrict__ slots, int* __restrict__ cnt) {
    int e = blockIdx.x;
    __shared__ int wsum[16];
    __shared__ int runbase;
    int t = threadIdx.x, wave = t >> 6, lane = t & 63;
    if (t == 0) runbase = 0;
    __syncthreads();
    for (int c0 = 0; c0 < NTOK; c0 += 1024) {
        int tok = c0 + t;
        int v = enc[tok];
        int e0 = v & 0xff, e1 = (v >> 8) & 0xff;
        bool sel = (e0 == e) || (e1 == e);
        unsigned long long m = __ballot(sel);
        int pos = __popcll(m & ((1ull << lane) - 1ull));
        if (lane == 0) wsum[wave] = __popcll(m);
        __syncthreads();
        int wb = runbase;
        for (int w = 0; w < wave; ++w) wb += wsum[w];
        if (sel) {
            int p = wb + pos;
            bidx[e * NTOK + p] = tok;
            int which = (e0 == e) ? 0 : 1;
            slots[2 * tok + which] = (e << 13) | p;
        }
        __syncthreads();
        if (t == 0) {
            int s = 0;
#pragma unroll
            for (int w = 0; w < 16; ++w) s += wsum[w];
            runbase += s;
        }
        __syncthreads();
    }
    if (t == 0) cnt[e] = runbase;
}

// inline 8-entry exclusive prefix of cnt up to e (uniform scalar loads)
__device__ __forceinline__ int prefix_cnt(const int* __restrict__ cnt, int e) {
    int s = 0;
    for (int i = 0; i < NE; ++i) s += (i < e) ? cnt[i] : 0;
    return s;
}

// ---------------- GEMM K-loop (shared by gemm1/gemm2) -----------------------
// 128x128 tile, BK=32, double-buffered: LDS = 2*(8K+8K) = 32 KB -> 5 blocks/CU
// (R5 post-mortem: 64KB dbuf capped residency at 2 blocks/CU; all pipes idle,
// latency exposed. TLP via residency is the fix.)
// LDS layout: 64 lines x 128B; line L packs rows {2L, 2L+1} K-slices (32 elem
// each) as 8 chunks of 16B, XOR-swizzled: slot = chunk ^ (L&7). 2-way bank
// aliasing at worst (free, m136).

// ---------------- GEMM1: H = relu(gather(Xb) @ W1 + b1), bf16 out ----------
__global__ __launch_bounds__(256) void gemm1_kernel(
    const unsigned short* __restrict__ xb, const unsigned short* __restrict__ w1T,
    const float* __restrict__ b1, const int* __restrict__ bidx,
    const int* __restrict__ cnt,
    unsigned short* __restrict__ H) {
    int b = blockIdx.x;
    int e = b & 7;          // XCD pin: all of expert e on XCD e
    int t2 = b >> 3;
    int nt = t2 & 7;
    int mt = t2 >> 3;
    int n_e = cnt[e];
    if (mt * 128 >= n_e) return;
    __shared__ __attribute__((aligned(16))) unsigned short As[2][64 * 64];
    __shared__ __attribute__((aligned(16))) unsigned short Bs[2][64 * 64];
    int t = threadIdx.x, wave = t >> 6, lane = t & 63;
    const int* be = bidx + e * NTOK;
    const unsigned short* agp[2]; const unsigned short* bgp[2];
    int ldsoff[2];
#pragma unroll
    for (int is = 0; is < 2; ++is) {
        int c = is * 256 + t;
        int line = c >> 3;
        int chunkg = (c & 7) ^ (line & 7);
        int growl = 2 * line + (chunkg >> 2);
        int gcol = (chunkg & 3) * 8;
        int gra = mt * 128 + growl;
        int grac = gra < n_e ? gra : n_e - 1;
        agp[is] = xb + (size_t)be[grac] * IN_DIM + gcol;
        bgp[is] = w1T + ((size_t)e * OUT_DIM + nt * 128 + growl) * IN_DIM + gcol;
        ldsoff[is] = (is * 256 + wave * 64) * 8; // elements; lane*16B appended by HW
    }
    int wm = wave & 1, wn = wave >> 1;
    int quad = lane >> 4, l15 = lane & 15;
    int lhalf = l15 >> 1;                       // = line&7 for all frags
    int slot = (((l15 & 1) * 4 + quad) ^ lhalf) * 8; // element offset in line
    f32x4 zero4 = {0.f, 0.f, 0.f, 0.f};
    f32x4 acc[4][4];
#pragma unroll
    for (int i = 0; i < 4; ++i)
#pragma unroll
        for (int j = 0; j < 4; ++j) acc[i][j] = zero4;

    // prologue: stage k-tile 0 into buffer 0
#pragma unroll
    for (int is = 0; is < 2; ++is) {
        async16(&As[0][ldsoff[is]], agp[is]);
        async16(&Bs[0][ldsoff[is]], bgp[is]);
    }
    for (int it = 0; it < 32; ++it) {
        __syncthreads();
        int buf = it & 1;
        if (it + 1 < 32) {
            int ktn = (it + 1) * 32;
#pragma unroll
            for (int is = 0; is < 2; ++is) {
                async16(&As[buf ^ 1][ldsoff[is]], agp[is] + ktn);
                async16(&Bs[buf ^ 1][ldsoff[is]], bgp[is] + ktn);
            }
        }
        const unsigned short* Ab = As[buf];
        const unsigned short* Bb = Bs[buf];
        bf16x8 av[4], bv[4];
#pragma unroll
        for (int i = 0; i < 4; ++i) {
            int lineA = wm * 32 + i * 8 + lhalf;
            av[i] = *(const bf16x8*)(Ab + lineA * 64 + slot);
        }
#pragma unroll
        for (int j = 0; j < 4; ++j) {
            int lineB = wn * 32 + j * 8 + lhalf;
            bv[j] = *(const bf16x8*)(Bb + lineB * 64 + slot);
        }
#pragma unroll
        for (int i = 0; i < 4; ++i)
#pragma unroll
            for (int j = 0; j < 4; ++j)
                acc[i][j] = __builtin_amdgcn_mfma_f32_16x16x32_bf16(av[i], bv[j], acc[i][j], 0, 0, 0);
    }
    // epilogue: + b1, relu, bf16 store to packed H
    int hbase = prefix_cnt(cnt, e);
    const float* b1e = b1 + (size_t)e * OUT_DIM;
    int n0 = nt * 128 + wn * 64 + l15;
#pragma unroll
    for (int j = 0; j < 4; ++j) {
        int n = n0 + j * 16;
        float bias = b1e[n];
#pragma unroll
        for (int i = 0; i < 4; ++i) {
            int m0 = mt * 128 + wm * 64 + i * 16 + quad * 4;
#pragma unroll
            for (int r = 0; r < 4; ++r) {
                int gm = m0 + r;
                if (gm < n_e) {
                    float h = acc[i][j][r] + bias;
                    h = h > 0.f ? h : 0.f;
                    H[(size_t)(hbase + gm) * OUT_DIM + n] = f2bf(h);
                }
            }
        }
    }
}

// ---------------- GEMM2: Y = H @ W2 (packed bf16, plain stores) -------------
__global__ __launch_bounds__(256) void gemm2_kernel(
    const unsigned short* __restrict__ H, const unsigned short* __restrict__ w2T,
    const int* __restrict__ cnt,
    unsigned short* __restrict__ Y) {
    int b = blockIdx.x;
    int e = b & 7;
    int t2 = b >> 3;
    int nt = t2 & 7;
    int mt = t2 >> 3;
    int n_e = cnt[e];
    if (mt * 128 >= n_e) return;
    __shared__ __attribute__((aligned(16))) unsigned short As[2][64 * 64];
    __shared__ __attribute__((aligned(16))) unsigned short Bs[2][64 * 64];
    int t = threadIdx.x, wave = t >> 6, lane = t & 63;
    int hbase = prefix_cnt(cnt, e);
    const unsigned short* agp[2]; const unsigned short* bgp[2];
    int ldsoff[2];
#pragma unroll
    for (int is = 0; is < 2; ++is) {
        int c = is * 256 + t;
        int line = c >> 3;
        int chunkg = (c & 7) ^ (line & 7);
        int growl = 2 * line + (chunkg >> 2);
        int gcol = (chunkg & 3) * 8;
        int gra = mt * 128 + growl;
        int grac = gra < n_e ? gra : n_e - 1;
        agp[is] = H + (size_t)(hbase + grac) * OUT_DIM + gcol;
        bgp[is] = w2T + ((size_t)e * OUT_DIM + nt * 128 + growl) * OUT_DIM + gcol;
        ldsoff[is] = (is * 256 + wave * 64) * 8;
    }
    int wm = wave & 1, wn = wave >> 1;
    int quad = lane >> 4, l15 = lane & 15;
    int lhalf = l15 >> 1;
    int slot = (((l15 & 1) * 4 + quad) ^ lhalf) * 8;
    f32x4 zero4 = {0.f, 0.f, 0.f, 0.f};
    f32x4 acc[4][4];
#pragma unroll
    for (int i = 0; i < 4; ++i)
#pragma unroll
        for (int j = 0; j < 4; ++j) acc[i][j] = zero4;

#pragma unroll
    for (int is = 0; is < 2; ++is) {
        async16(&As[0][ldsoff[is]], agp[is]);
        async16(&Bs[0][ldsoff[is]], bgp[is]);
    }
    for (int it = 0; it < 32; ++it) {
        __syncthreads();
        int buf = it & 1;
        if (it + 1 < 32) {
            int ktn = (it + 1) * 32;
#pragma unroll
            for (int is = 0; is < 2; ++is) {
                async16(&As[buf ^ 1][ldsoff[is]], agp[is] + ktn);
                async16(&Bs[buf ^ 1][ldsoff[is]], bgp[is] + ktn);
            }
        }
        const unsigned short* Ab = As[buf];
        const unsigned short* Bb = Bs[buf];
        bf16x8 av[4], bv[4];
#pragma unroll
        for (int i = 0; i < 4; ++i) {
            int lineA = wm * 32 + i * 8 + lhalf;
            av[i] = *(const bf16x8*)(Ab + lineA * 64 + slot);
        }
#pragma unroll
        for (int j = 0; j < 4; ++j) {
            int lineB = wn * 32 + j * 8 + lhalf;
            bv[j] = *(const bf16x8*)(Bb + lineB * 64 + slot);
        }
#pragma unroll
        for (int i = 0; i < 4; ++i)
#pragma unroll
            for (int j = 0; j < 4; ++j)
                acc[i][j] = __builtin_amdgcn_mfma_f32_16x16x32_bf16(av[i], bv[j], acc[i][j], 0, 0, 0);
    }
    // epilogue: plain bf16 stores to packed Y
    int n0 = nt * 128 + wn * 64 + l15;
#pragma unroll
    for (int i = 0; i < 4; ++i) {
        int m0 = mt * 128 + wm * 64 + i * 16 + quad * 4;
#pragma unroll
        for (int r = 0; r < 4; ++r) {
            int gm = m0 + r;
            if (gm < n_e) {
                unsigned short* yrow = Y + (size_t)(hbase + gm) * OUT_DIM;
#pragma unroll
                for (int j = 0; j < 4; ++j)
                    yrow[n0 + j * 16] = f2bf(acc[i][j][r]);
            }
        }
    }
}

// ---------------- combine: out[tok] = g0*(Y[r0]+b2[e0]) + g1*(Y[r1]+b2[e1]) -
__global__ __launch_bounds__(256) void combine_kernel(
    const unsigned short* __restrict__ Y, const float* __restrict__ b2,
    const float2* __restrict__ gw, const int* __restrict__ slots,
    const int* __restrict__ cnt, float* __restrict__ out) {
    int t = threadIdx.x, wave = t >> 6, lane = t & 63;
    int tok = blockIdx.x * 4 + wave;
    int pre[NE];
    {
        int s = 0;
#pragma unroll
        for (int i = 0; i < NE; ++i) { pre[i] = s; s += cnt[i]; }
    }
    int s0 = slots[2 * tok], s1 = slots[2 * tok + 1];
    int e0 = s0 >> 13, e1 = s1 >> 13;
    int r0 = pre[e0] + (s0 & 8191);
    int r1 = pre[e1] + (s1 & 8191);
    float2 g = gw[tok];
    const unsigned short* y0 = Y + (size_t)r0 * OUT_DIM;
    const unsigned short* y1 = Y + (size_t)r1 * OUT_DIM;
    const float* c0 = b2 + (size_t)e0 * OUT_DIM;
    const float* c1 = b2 + (size_t)e1 * OUT_DIM;
    float* orow = out + (size_t)tok * OUT_DIM;
#pragma unroll
    for (int i = 0; i < 2; ++i) {
        int c = i * 512 + lane * 8;
        uint4 ua = *(const uint4*)(y0 + c);
        uint4 ub = *(const uint4*)(y1 + c);
        float a[8], b[8];
        bf2x(ua.x, a[0], a[1]); bf2x(ua.y, a[2], a[3]);
        bf2x(ua.z, a[4], a[5]); bf2x(ua.w, a[6], a[7]);
        bf2x(ub.x, b[0], b[1]); bf2x(ub.y, b[2], b[3]);
        bf2x(ub.z, b[4], b[5]); bf2x(ub.w, b[6], b[7]);
        float4 p0 = *(const float4*)(c0 + c);
        float4 p1 = *(const float4*)(c0 + c + 4);
        float4 q0 = *(const float4*)(c1 + c);
        float4 q1 = *(const float4*)(c1 + c + 4);
        float o[8];
        o[0] = g.x * (a[0] + p0.x) + g.y * (b[0] + q0.x);
        o[1] = g.x * (a[1] + p0.y) + g.y * (b[1] + q0.y);
        o[2] = g.x * (a[2] + p0.z) + g.y * (b[2] + q0.z);
        o[3] = g.x * (a[3] + p0.w) + g.y * (b[3] + q0.w);
        o[4] = g.x * (a[4] + p1.x) + g.y * (b[4] + q1.x);
        o[5] = g.x * (a[5] + p1.y) + g.y * (b[5] + q1.y);
        o[6] = g.x * (a[6] + p1.z) + g.y * (b[6] + q1.z);
        o[7] = g.x * (a[7] + p1.w) + g.y * (b[7] + q1.w);
        *(float4*)(orow + c) = make_float4(o[0], o[1], o[2], o[3]);
        *(float4*)(orow + c + 4) = make_float4(o[4], o[5], o[6], o[7]);
    }
}

extern "C" void kernel_launch(void* const* d_in, const int* in_sizes, int n_in,
                              void* d_out, int out_size, void* d_ws, size_t ws_size,
                              hipStream_t stream) {
    const float* x  = (const float*)d_in[0];
    const float* rw = (const float*)d_in[1];
    const float* rb = (const float*)d_in[2];
    const float* w1 = (const float*)d_in[3];
    const float* b1 = (const float*)d_in[4];
    const float* w2 = (const float*)d_in[5];
    const float* b2 = (const float*)d_in[6];
    float* out = (float*)d_out;                       // fused [8192,1024]
    float* gating = out + (size_t)NTOK * OUT_DIM;     // gating [8192,8]

    char* ws = (char*)d_ws;
    // ws layout (bytes). Y reuses [0,32MiB): xb+w1T dead after gemm1
    // (stream-ordered). enc/gw outside H region.
    unsigned short* xb  = (unsigned short*)(ws + 0);          // 16 MiB
    unsigned short* Y   = (unsigned short*)(ws + 0);          // 32 MiB (gemm2+)
    unsigned short* w1T = (unsigned short*)(ws + 16777216);   // 16 MiB
    unsigned short* w2T = (unsigned short*)(ws + 33554432);   // 16 MiB
    unsigned short* H   = (unsigned short*)(ws + 50331648);   // 32 MiB
    int*   bidx  = (int*)(ws + 83886080);                     // 256 KiB
    int*   slots = (int*)(ws + 84148224);                     // 64 KiB
    int*   cnt   = (int*)(ws + 84213760);                     // 64 B
    int*    enc  = (int*)(ws + 84213888);                     // 32 KiB
    float2* gw   = (float2*)(ws + 84246656);                  // 64 KiB

    convert_transpose_kernel<<<dim3(16, 16, 16), 256, 0, stream>>>(w1, w2, w1T, w2T);
    router_kernel<<<NTOK / 4, 256, 0, stream>>>(x, rw, rb, xb, gating, enc, gw);
    bucket_kernel<<<NE, 1024, 0, stream>>>(enc, bidx, slots, cnt);
    gemm1_kernel<<<8 * 8 * 64, 256, 0, stream>>>(xb, w1T, b1, bidx, cnt, H);
    gemm2_kernel<<<8 * 8 * 64, 256, 0, stream>>>(H, w2T, cnt, Y);
    combine_kernel<<<NTOK / 4, 256, 0, stream>>>(Y, b2, gw, slots, cnt, out);
    (void)in_sizes; (void)n_in; (void)out_size; (void)ws_size;
}